// Round 4
// baseline (3444.944 us; speedup 1.0000x reference)
//
#include <hip/hip_runtime.h>
#include <hip/hip_bf16.h>
#include <math.h>

typedef __bf16 bf16;
typedef bf16 bf16x8 __attribute__((ext_vector_type(8)));
typedef float f32x4 __attribute__((ext_vector_type(4)));

#define NPT 1365
#define HD 512

__device__ __forceinline__ float sigm(float x){ return 1.0f/(1.0f+__expf(-x)); }

// ---------------- split fp32 -> bf16 hi/lo ----------------
__global__ void k_split(const float* __restrict__ s, bf16* __restrict__ hi,
                        bf16* __restrict__ lo, size_t n){
  size_t i=(size_t)blockIdx.x*blockDim.x+threadIdx.x;
  if(i<n){ float v=s[i]; bf16 h=(bf16)v; hi[i]=h; lo[i]=(bf16)(v-(float)h); }
}

// ---------------- internal weight concat: [Whi|Whi|Uhi|Uhi|Wlo|Ulo], K=3840 ----------------
__global__ void k_concatHL(const float* __restrict__ W, const float* __restrict__ U,
                           bf16* __restrict__ d, int rows){
  size_t i=(size_t)blockIdx.x*blockDim.x+threadIdx.x;
  const int K=3840;
  size_t tot=(size_t)rows*K;
  if(i>=tot) return;
  int r=(int)(i/K); int k=(int)(i-(size_t)r*K);
  float v; int lo=0;
  if(k<768)        v=W[(size_t)r*768+k];
  else if(k<1536)  v=W[(size_t)r*768+(k-768)];
  else if(k<2048)  v=U[(size_t)r*512+(k-1536)];
  else if(k<2560)  v=U[(size_t)r*512+(k-2048)];
  else if(k<3328){ v=W[(size_t)r*768+(k-2560)]; lo=1; }
  else           { v=U[(size_t)r*512+(k-3328)]; lo=1; }
  bf16 h=(bf16)v;
  d[i]= lo ? (bf16)(v-(float)h) : h;
}

// ---------------- leaf weight concat: [Whi|Whi|Wlo], K=2304 ----------------
__global__ void k_concatLeaf(const float* __restrict__ W, bf16* __restrict__ d, int rows){
  size_t i=(size_t)blockIdx.x*blockDim.x+threadIdx.x;
  const int K=2304;
  size_t tot=(size_t)rows*K;
  if(i>=tot) return;
  int r=(int)(i/K); int k=(int)(i-(size_t)r*K);
  int kk=(k<768)?k:((k<1536)?k-768:k-1536);
  float v=W[(size_t)r*768+kk];
  bf16 h=(bf16)v;
  d[i]=(k<1536)? h : (bf16)(v-(float)h);
}

// ---------------- Wcomb = W_sd2 @ W_sd  (512x512, fp32 exact) ----------------
__global__ __launch_bounds__(256)
void k_wcomb(const float* __restrict__ W2, const float* __restrict__ W1,
             float* __restrict__ out){
  __shared__ float As[64][33];
  __shared__ float Bs[32][65];
  const int tid=threadIdx.x;
  const int i0=blockIdx.x*64, j0=blockIdx.y*64;
  const int tr=(tid>>4)*4, tc=(tid&15)*4;
  float acc[4][4];
  #pragma unroll
  for(int x=0;x<4;++x)
    #pragma unroll
    for(int y=0;y<4;++y) acc[x][y]=0.f;
  for(int k0=0;k0<1024;k0+=32){
    for(int l=tid;l<64*32;l+=256){ int r=l>>5,c=l&31; As[r][c]=W2[(size_t)(i0+r)*1024+k0+c]; }
    for(int l=tid;l<32*64;l+=256){ int r=l>>6,c=l&63; Bs[r][c]=W1[(size_t)(k0+r)*512+j0+c]; }
    __syncthreads();
    #pragma unroll 8
    for(int k=0;k<32;++k){
      float a[4],b[4];
      #pragma unroll
      for(int x=0;x<4;++x){ a[x]=As[tr+x][k]; b[x]=Bs[k][tc+x]; }
      #pragma unroll
      for(int x=0;x<4;++x)
        #pragma unroll
        for(int y=0;y<4;++y) acc[x][y]+=a[x]*b[y];
    }
    __syncthreads();
  }
  #pragma unroll
  for(int x=0;x<4;++x)
    #pragma unroll
    for(int y=0;y<4;++y) out[(size_t)(i0+tr+x)*512+j0+tc+y]=acc[x][y];
}

// ---------------- h_sum: fp32 sum of 4 children (hi+lo), split hi/lo ----------------
__global__ __launch_bounds__(256)
void k_hsum(const bf16* __restrict__ hhi, const bf16* __restrict__ hlo,
            bf16* __restrict__ hs_hi, bf16* __restrict__ hs_lo,
            int start_ch, int lcm1, int P){
  int idx=blockIdx.x*256+threadIdx.x;
  int m=idx>>6;
  if(m>=P) return;
  int c8=(idx&63)*8;
  int cm=m<<2;
  int t=cm>>lcm1, ci=cm-(t<<lcm1);
  const size_t base=((size_t)t*NPT+start_ch+ci)*HD+c8;
  float s[8];
  #pragma unroll
  for(int e=0;e<8;++e) s[e]=0.f;
  #pragma unroll
  for(int ch=0;ch<4;++ch){
    bf16x8 a=*(const bf16x8*)(hhi+base+(size_t)ch*HD);
    bf16x8 b=*(const bf16x8*)(hlo+base+(size_t)ch*HD);
    #pragma unroll
    for(int e=0;e<8;++e) s[e]+=(float)a[e]+(float)b[e];
  }
  bf16x8 oh,ol;
  #pragma unroll
  for(int e=0;e<8;++e){ bf16 hv=(bf16)s[e]; oh[e]=hv; ol[e]=(bf16)(s[e]-(float)hv); }
  *(bf16x8*)(hs_hi+(size_t)m*HD+c8)=oh;
  *(bf16x8*)(hs_lo+(size_t)m*HD+c8)=ol;
}

// ---------------- iou GEMM + gate epilogue ----------------
// internal: A=[fH|fL|hsH|hsL|fH|hsH] K=3840 ; leaf: A=[fH|fL|fH] K=2304
__global__ __launch_bounds__(256)
void k_iou(const bf16* __restrict__ fH, const bf16* __restrict__ fL,
           const bf16* __restrict__ hsH, const bf16* __restrict__ hsL,
           const bf16* __restrict__ Wcat, const float* __restrict__ bias,
           const float* __restrict__ csum, bf16* __restrict__ hbuf,
           bf16* __restrict__ hlo, float* __restrict__ cbuf,
           int start_n, int shift, int K, int KB, int internal)
{
  __shared__ bf16 As[64][40];
  __shared__ bf16 Bs[3][64][40];
  const int tid=threadIdx.x;
  const int m0=blockIdx.x*64, n0=blockIdx.y*64;
  const int srow=tid>>2, skc=(tid&3)*8;
  const int m=m0+srow;
  const int t=m>>shift, j=m-(t<<shift);
  const size_t frow=((size_t)t*NPT+start_n+j)*768;
  const bf16* aFH=fH+frow;
  const bf16* aFL=fL+frow;
  const bf16* aHH=hsH+(size_t)m*HD;
  const bf16* aHL=hsL+(size_t)m*HD;
  const bf16* bp0=Wcat+(size_t)(n0+srow)*KB;
  const bf16* bp1=Wcat+(size_t)(512+n0+srow)*KB;
  const bf16* bp2=Wcat+(size_t)(1024+n0+srow)*KB;

  f32x4 acc[3][2][2];
  #pragma unroll
  for(int g=0;g<3;++g)
    #pragma unroll
    for(int mi=0;mi<2;++mi)
      #pragma unroll
      for(int ni=0;ni<2;++ni) acc[g][mi][ni]=(f32x4){0.f,0.f,0.f,0.f};

  const int w=tid>>6, lane=tid&63;
  const int wr=(w>>1)*32, wc=(w&1)*32;
  const int lr=lane&15, lg=lane>>4;

  for(int k0=0;k0<K;k0+=32){
    const bf16* ap;
    if(internal){
      if(k0<768)        ap=aFH+k0;
      else if(k0<1536)  ap=aFL+(k0-768);
      else if(k0<2048)  ap=aHH+(k0-1536);
      else if(k0<2560)  ap=aHL+(k0-2048);
      else if(k0<3328)  ap=aFH+(k0-2560);
      else              ap=aHH+(k0-3328);
    }else{
      ap=(k0<768)? (aFH+k0) : ((k0<1536)? (aFL+(k0-768)) : (aFH+(k0-1536)));
    }
    *(bf16x8*)&As[srow][skc]=*(const bf16x8*)(ap+skc);
    *(bf16x8*)&Bs[0][srow][skc]=*(const bf16x8*)(bp0+k0+skc);
    *(bf16x8*)&Bs[1][srow][skc]=*(const bf16x8*)(bp1+k0+skc);
    *(bf16x8*)&Bs[2][srow][skc]=*(const bf16x8*)(bp2+k0+skc);
    __syncthreads();
    bf16x8 a0=*(bf16x8*)&As[wr+lr][lg*8];
    bf16x8 a1=*(bf16x8*)&As[wr+16+lr][lg*8];
    #pragma unroll
    for(int g=0;g<3;++g){
      #pragma unroll
      for(int ni=0;ni<2;++ni){
        bf16x8 bv=*(bf16x8*)&Bs[g][wc+ni*16+lr][lg*8];
        acc[g][0][ni]=__builtin_amdgcn_mfma_f32_16x16x32_bf16(a0,bv,acc[g][0][ni],0,0,0);
        acc[g][1][ni]=__builtin_amdgcn_mfma_f32_16x16x32_bf16(a1,bv,acc[g][1][ni],0,0,0);
      }
    }
    __syncthreads();
  }

  #pragma unroll
  for(int mi=0;mi<2;++mi){
    #pragma unroll
    for(int ni=0;ni<2;++ni){
      const int col=n0+wc+ni*16+lr;
      const float bi=bias[col], bo=bias[col+512], bu=bias[col+1024];
      #pragma unroll
      for(int r=0;r<4;++r){
        const int mm=m0+wr+mi*16+lg*4+r;
        float iv=acc[0][mi][ni][r]+bi;
        float ov=acc[1][mi][ni][r]+bo;
        float uv=acc[2][mi][ni][r]+bu;
        float cn=sigm(iv)*tanhf(uv);
        if(internal) cn+=csum[(size_t)mm*HD+col];
        float hn=sigm(ov)*tanhf(cn);
        const int tt=mm>>shift, jj=mm-(tt<<shift);
        const size_t nd=((size_t)tt*NPT+start_n+jj)*HD+col;
        cbuf[nd]=cn;
        bf16 hh=(bf16)hn;
        hbuf[nd]=hh;
        hlo[nd]=(bf16)(hn-(float)hh);
      }
    }
  }
}

// ---------------- forget-gate GEMM + fused f*c_child 4-row reduce ----------------
// A=[fpH|fpL|chH|chL|fpH|chH] K=3840, B=[WfH|WfH|UfH|UfH|WfL|UfL]
__global__ __launch_bounds__(256)
void k_f(const bf16* __restrict__ fH, const bf16* __restrict__ fL,
         const bf16* __restrict__ hhi, const bf16* __restrict__ hlo,
         const bf16* __restrict__ Wcatf, const float* __restrict__ bias,
         const float* __restrict__ cbuf, float* __restrict__ csum,
         int start_par, int start_ch, int lc)
{
  __shared__ bf16 As[64][40];
  __shared__ bf16 Bs[64][40];
  const int tid=threadIdx.x;
  const int e0=blockIdx.x*64, n0=blockIdx.y*64;
  const int srow=tid>>2, skc=(tid&3)*8;
  const int e=e0+srow;
  const int t=e>>lc, ei=e-(t<<lc);
  const size_t frow=((size_t)t*NPT+start_par+(ei>>2))*768;
  const size_t hrow=((size_t)t*NPT+start_ch+ei)*HD;
  const bf16* aFH=fH+frow;
  const bf16* aFL=fL+frow;
  const bf16* aHH=hhi+hrow;
  const bf16* aHL=hlo+hrow;
  const bf16* bp=Wcatf+(size_t)(n0+srow)*3840;

  f32x4 acc[2][2];
  #pragma unroll
  for(int mi=0;mi<2;++mi)
    #pragma unroll
    for(int ni=0;ni<2;++ni) acc[mi][ni]=(f32x4){0.f,0.f,0.f,0.f};

  const int w=tid>>6, lane=tid&63;
  const int wr=(w>>1)*32, wc=(w&1)*32;
  const int lr=lane&15, lg=lane>>4;

  for(int k0=0;k0<3840;k0+=32){
    const bf16* ap;
    if(k0<768)        ap=aFH+k0;
    else if(k0<1536)  ap=aFL+(k0-768);
    else if(k0<2048)  ap=aHH+(k0-1536);
    else if(k0<2560)  ap=aHL+(k0-2048);
    else if(k0<3328)  ap=aFH+(k0-2560);
    else              ap=aHH+(k0-3328);
    *(bf16x8*)&As[srow][skc]=*(const bf16x8*)(ap+skc);
    *(bf16x8*)&Bs[srow][skc]=*(const bf16x8*)(bp+k0+skc);
    __syncthreads();
    bf16x8 a0=*(bf16x8*)&As[wr+lr][lg*8];
    bf16x8 a1=*(bf16x8*)&As[wr+16+lr][lg*8];
    #pragma unroll
    for(int ni=0;ni<2;++ni){
      bf16x8 bv=*(bf16x8*)&Bs[wc+ni*16+lr][lg*8];
      acc[0][ni]=__builtin_amdgcn_mfma_f32_16x16x32_bf16(a0,bv,acc[0][ni],0,0,0);
      acc[1][ni]=__builtin_amdgcn_mfma_f32_16x16x32_bf16(a1,bv,acc[1][ni],0,0,0);
    }
    __syncthreads();
  }

  #pragma unroll
  for(int mi=0;mi<2;++mi){
    const int ebase=e0+wr+mi*16+lg*4;
    const int tt=ebase>>lc, eib=ebase-(tt<<lc);
    #pragma unroll
    for(int ni=0;ni<2;++ni){
      const int col=n0+wc+ni*16+lr;
      const float bb=bias[col];
      const size_t chbase=((size_t)tt*NPT+start_ch+eib)*HD+col;
      float s=0.f;
      #pragma unroll
      for(int r=0;r<4;++r){
        float fv=sigm(acc[mi][ni][r]+bb);
        s+=fv*cbuf[chbase+(size_t)r*HD];
      }
      csum[((size_t)(ebase>>2))*HD+col]=s;
    }
  }
}

// ---------------- stance GEMM: h_st = h @ Wcomb^T + h  (split precision, fp32 out) ----------------
__global__ __launch_bounds__(256)
void k_stance(const bf16* __restrict__ Ahi, const bf16* __restrict__ Alo,
              const bf16* __restrict__ Bhi, const bf16* __restrict__ Blo,
              float* __restrict__ C)
{
  __shared__ bf16 AsH[64][40];
  __shared__ bf16 AsL[64][40];
  __shared__ bf16 BsH[64][40];
  __shared__ bf16 BsL[64][40];
  const int tid=threadIdx.x;
  const int m0=blockIdx.x*64, n0=blockIdx.y*64;
  const int srow=tid>>2, skc=(tid&3)*8;
  const bf16* ah=Ahi+(size_t)(m0+srow)*HD;
  const bf16* al=Alo+(size_t)(m0+srow)*HD;
  const bf16* bh=Bhi+(size_t)(n0+srow)*HD;
  const bf16* bl=Blo+(size_t)(n0+srow)*HD;

  f32x4 acc[2][2];
  #pragma unroll
  for(int mi=0;mi<2;++mi)
    #pragma unroll
    for(int ni=0;ni<2;++ni) acc[mi][ni]=(f32x4){0.f,0.f,0.f,0.f};

  const int w=tid>>6, lane=tid&63;
  const int wr=(w>>1)*32, wc=(w&1)*32;
  const int lr=lane&15, lg=lane>>4;

  for(int k0=0;k0<HD;k0+=32){
    *(bf16x8*)&AsH[srow][skc]=*(const bf16x8*)(ah+k0+skc);
    *(bf16x8*)&AsL[srow][skc]=*(const bf16x8*)(al+k0+skc);
    *(bf16x8*)&BsH[srow][skc]=*(const bf16x8*)(bh+k0+skc);
    *(bf16x8*)&BsL[srow][skc]=*(const bf16x8*)(bl+k0+skc);
    __syncthreads();
    #pragma unroll
    for(int mi=0;mi<2;++mi){
      bf16x8 avh=*(bf16x8*)&AsH[wr+mi*16+lr][lg*8];
      bf16x8 avl=*(bf16x8*)&AsL[wr+mi*16+lr][lg*8];
      #pragma unroll
      for(int ni=0;ni<2;++ni){
        bf16x8 bvh=*(bf16x8*)&BsH[wc+ni*16+lr][lg*8];
        bf16x8 bvl=*(bf16x8*)&BsL[wc+ni*16+lr][lg*8];
        acc[mi][ni]=__builtin_amdgcn_mfma_f32_16x16x32_bf16(avh,bvh,acc[mi][ni],0,0,0);
        acc[mi][ni]=__builtin_amdgcn_mfma_f32_16x16x32_bf16(avl,bvh,acc[mi][ni],0,0,0);
        acc[mi][ni]=__builtin_amdgcn_mfma_f32_16x16x32_bf16(avh,bvl,acc[mi][ni],0,0,0);
      }
    }
    __syncthreads();
  }

  #pragma unroll
  for(int mi=0;mi<2;++mi){
    #pragma unroll
    for(int ni=0;ni<2;++ni){
      const int col=n0+wc+ni*16+lr;
      #pragma unroll
      for(int r=0;r<4;++r){
        const int mm=m0+wr+mi*16+lg*4+r;
        const size_t idx=(size_t)mm*HD+col;
        C[idx]=acc[mi][ni][r]+(float)Ahi[idx]+(float)Alo[idx];
      }
    }
  }
}

// ---------------- final: y = h_st @ W_sf^T, LayerNorm(4), softmax (all fp32) ----------------
__global__ __launch_bounds__(256)
void k_final(const float* __restrict__ hst, const float* __restrict__ Wsf,
             const float* __restrict__ gamma, const float* __restrict__ beta,
             float* __restrict__ out0, int Nn)
{
  const int gtid=blockIdx.x*256+threadIdx.x;
  const int node=gtid>>6, lane=gtid&63;
  if(node>=Nn) return;
  const float* hp=hst+(size_t)node*HD+lane*8;
  float hf[8];
  #pragma unroll
  for(int e=0;e<8;++e) hf[e]=hp[e];
  float y[4];
  #pragma unroll
  for(int jj=0;jj<4;++jj){
    const float* wp=Wsf+jj*HD+lane*8;
    float s=0.f;
    #pragma unroll
    for(int e=0;e<8;++e) s+=hf[e]*wp[e];
    #pragma unroll
    for(int off=32;off>=1;off>>=1) s+=__shfl_xor(s,off,64);
    y[jj]=s;
  }
  if(lane==0){
    float mu=0.25f*(y[0]+y[1]+y[2]+y[3]);
    float var=0.f;
    #pragma unroll
    for(int jj=0;jj<4;++jj){ float d=y[jj]-mu; var+=d*d; }
    var*=0.25f;
    float rs=rsqrtf(var+1e-6f);
    float z[4], zmax=-1e30f;
    #pragma unroll
    for(int jj=0;jj<4;++jj){ z[jj]=(y[jj]-mu)*rs*gamma[jj]+beta[jj]; zmax=fmaxf(zmax,z[jj]); }
    float es=0.f;
    #pragma unroll
    for(int jj=0;jj<4;++jj){ z[jj]=__expf(z[jj]-zmax); es+=z[jj]; }
    float inv=1.f/es;
    #pragma unroll
    for(int jj=0;jj<4;++jj) out0[(size_t)node*4+jj]=z[jj]*inv;
  }
}

// ---------------- root head: softmax(h[root] @ W_ff^T), fp32 h via hi+lo ----------------
__global__ __launch_bounds__(256)
void k_root(const bf16* __restrict__ hhi, const bf16* __restrict__ hlo,
            const float* __restrict__ Wff, float* __restrict__ out1)
{
  const int gtid=blockIdx.x*256+threadIdx.x;
  const int tt=gtid>>6, lane=gtid&63;
  if(tt>=64) return;
  const size_t base=((size_t)tt*NPT+1364)*HD+lane*8;
  bf16x8 hv=*(const bf16x8*)(hhi+base);
  bf16x8 lv=*(const bf16x8*)(hlo+base);
  float hf[8];
  #pragma unroll
  for(int e=0;e<8;++e) hf[e]=(float)hv[e]+(float)lv[e];
  float y[4];
  #pragma unroll
  for(int jj=0;jj<4;++jj){
    const float* wp=Wff+jj*HD+lane*8;
    float s=0.f;
    #pragma unroll
    for(int e=0;e<8;++e) s+=hf[e]*wp[e];
    #pragma unroll
    for(int off=32;off>=1;off>>=1) s+=__shfl_xor(s,off,64);
    y[jj]=s;
  }
  if(lane==0){
    float zmax=fmaxf(fmaxf(y[0],y[1]),fmaxf(y[2],y[3]));
    float es=0.f, z[4];
    #pragma unroll
    for(int jj=0;jj<4;++jj){ z[jj]=__expf(y[jj]-zmax); es+=z[jj]; }
    float inv=1.f/es;
    #pragma unroll
    for(int jj=0;jj<4;++jj) out1[(size_t)tt*4+jj]=z[jj]*inv;
  }
}

extern "C" void kernel_launch(void* const* d_in, const int* in_sizes, int n_in,
                              void* d_out, int out_size, void* d_ws, size_t ws_size,
                              hipStream_t stream)
{
  const float* features=(const float*)d_in[0];
  const float* W_iou=(const float*)d_in[6];
  const float* b_iou=(const float*)d_in[7];
  const float* U_iou=(const float*)d_in[8];
  const float* W_f  =(const float*)d_in[9];
  const float* b_f  =(const float*)d_in[10];
  const float* U_f  =(const float*)d_in[11];
  const float* W_ff =(const float*)d_in[12];
  const float* W_sd =(const float*)d_in[13];
  const float* W_sd2=(const float*)d_in[14];
  const float* W_sf =(const float*)d_in[15];
  const float* ln_g =(const float*)d_in[16];
  const float* ln_b =(const float*)d_in[17];

  const int N=in_sizes[0]/768;   // 87360
  const int T=N/NPT;             // 64

  float* out0=(float*)d_out;
  float* out1=out0+(size_t)N*4;
  float* cbuf=out1+(size_t)T*4;  // c output region, used as live c-state

  char* p=(char*)d_ws;
  auto alloc=[&](size_t bytes){ char* r=p; p+=((bytes+255)&~(size_t)255); return r; };
  // region A — dead after the tree pass; reused for fp32 hst
  char*  regionA=p;
  bf16*  f_hi =(bf16*) alloc((size_t)N*768*2);        // 134.2 MB
  bf16*  f_lo =(bf16*) alloc((size_t)N*768*2);        // 134.2 MB
  // persistent region
  bf16*  hs_hi=(bf16*) alloc((size_t)16384*HD*2);     // 16.8 MB
  bf16*  hs_lo=(bf16*) alloc((size_t)16384*HD*2);     // 16.8 MB
  float* csum =(float*)alloc((size_t)16384*HD*4);     // 33.6 MB
  bf16*  h_hi =(bf16*) alloc((size_t)N*HD*2);         // 89.5 MB
  bf16*  h_lo =(bf16*) alloc((size_t)N*HD*2);         // 89.5 MB
  bf16*  WcatI=(bf16*) alloc((size_t)1536*3840*2);    // 11.8 MB
  bf16*  WlfI =(bf16*) alloc((size_t)1536*2304*2);    //  7.1 MB
  bf16*  WcatF=(bf16*) alloc((size_t)512*3840*2);     //  3.9 MB
  float* Wcomb=(float*)alloc((size_t)512*512*4);
  bf16*  Wc_hi=(bf16*) alloc((size_t)512*512*2);
  bf16*  Wc_lo=(bf16*) alloc((size_t)512*512*2);
  float* hst  =(float*)regionA;  // N*HD*4 = 178.9 MB <= f_hi+f_lo span (268 MB)

  // conversions / weight prep
  { size_t n=(size_t)N*768;     k_split<<<(int)((n+255)/256),256,0,stream>>>(features,f_hi,f_lo,n); }
  { size_t n=(size_t)1536*3840; k_concatHL<<<(int)((n+255)/256),256,0,stream>>>(W_iou,U_iou,WcatI,1536); }
  { size_t n=(size_t)1536*2304; k_concatLeaf<<<(int)((n+255)/256),256,0,stream>>>(W_iou,WlfI,1536); }
  { size_t n=(size_t)512*3840;  k_concatHL<<<(int)((n+255)/256),256,0,stream>>>(W_f,U_f,WcatF,512); }
  { dim3 g(8,8); k_wcomb<<<g,256,0,stream>>>(W_sd2,W_sd,Wcomb); }
  { size_t n=(size_t)512*512;   k_split<<<(int)((n+255)/256),256,0,stream>>>(Wcomb,Wc_hi,Wc_lo,n); }

  static const int starts[6]={0,1024,1280,1344,1360,1364};
  static const int csh[6]  ={10,8,6,4,2,0};
  static const int counts[6]={1024,256,64,16,4,1};

  // level 0 (leaves): A=[fH|fL|fH] K=2304
  { dim3 g((T*1024)/64, 8);
    k_iou<<<g,256,0,stream>>>(f_hi,f_lo,hs_hi,hs_lo,WlfI,b_iou,csum,h_hi,h_lo,cbuf,0,10,2304,2304,0); }

  for(int n=1;n<6;++n){
    int P=T*counts[n], E=T*counts[n-1];
    { int th=P*64; k_hsum<<<(th+255)/256,256,0,stream>>>(h_hi,h_lo,hs_hi,hs_lo,starts[n-1],csh[n-1],P); }
    { dim3 g(E/64,8);
      k_f<<<g,256,0,stream>>>(f_hi,f_lo,h_hi,h_lo,WcatF,b_f,cbuf,csum,starts[n],starts[n-1],csh[n-1]); }
    { dim3 g(P/64,8);
      k_iou<<<g,256,0,stream>>>(f_hi,f_lo,hs_hi,hs_lo,WcatI,b_iou,csum,h_hi,h_lo,cbuf,starts[n],csh[n],3840,3840,1); }
  }

  // stance: h_st = h @ Wcomb^T + h  (split-precision, fp32 out)
  { dim3 g(N/64, 8);
    k_stance<<<g,256,0,stream>>>(h_hi,h_lo,Wc_hi,Wc_lo,hst); }

  // heads
  { int th=N*64; k_final<<<(th+255)/256,256,0,stream>>>(hst,W_sf,ln_g,ln_b,out0,N); }
  { k_root<<<16,256,0,stream>>>(h_hi,h_lo,W_ff,out1); }
}

// Round 5
// 2999.504 us; speedup vs baseline: 1.1485x; 1.1485x over previous
//
#include <hip/hip_runtime.h>
#include <hip/hip_bf16.h>
#include <math.h>

typedef __bf16 bf16;
typedef bf16 bf16x8 __attribute__((ext_vector_type(8)));
typedef float f32x4 __attribute__((ext_vector_type(4)));

#define NPT 1365
#define HD 512

__device__ __forceinline__ float sigm(float x){ return 1.0f/(1.0f+__expf(-x)); }

// async global->LDS, 16B per lane; lds dest must be wave-uniform base (lane*16 applied by HW)
__device__ __forceinline__ void gll16(const void* g, void* l){
  __builtin_amdgcn_global_load_lds((const __attribute__((address_space(1))) void*)g,
                                   (__attribute__((address_space(3))) void*)l, 16, 0, 0);
}

// ---------------- split fp32 -> bf16 hi/lo ----------------
__global__ void k_split(const float* __restrict__ s, bf16* __restrict__ hi,
                        bf16* __restrict__ lo, size_t n){
  size_t i=(size_t)blockIdx.x*blockDim.x+threadIdx.x;
  if(i<n){ float v=s[i]; bf16 h=(bf16)v; hi[i]=h; lo[i]=(bf16)(v-(float)h); }
}

// ---------------- internal weight concat: [Whi|Whi|Uhi|Uhi|Wlo|Ulo], K=3840 ----------------
__global__ void k_concatHL(const float* __restrict__ W, const float* __restrict__ U,
                           bf16* __restrict__ d, int rows){
  size_t i=(size_t)blockIdx.x*blockDim.x+threadIdx.x;
  const int K=3840;
  size_t tot=(size_t)rows*K;
  if(i>=tot) return;
  int r=(int)(i/K); int k=(int)(i-(size_t)r*K);
  float v; int lo=0;
  if(k<768)        v=W[(size_t)r*768+k];
  else if(k<1536)  v=W[(size_t)r*768+(k-768)];
  else if(k<2048)  v=U[(size_t)r*512+(k-1536)];
  else if(k<2560)  v=U[(size_t)r*512+(k-2048)];
  else if(k<3328){ v=W[(size_t)r*768+(k-2560)]; lo=1; }
  else           { v=U[(size_t)r*512+(k-3328)]; lo=1; }
  bf16 h=(bf16)v;
  d[i]= lo ? (bf16)(v-(float)h) : h;
}

// ---------------- leaf weight concat: [Whi|Whi|Wlo], K=2304 ----------------
__global__ void k_concatLeaf(const float* __restrict__ W, bf16* __restrict__ d, int rows){
  size_t i=(size_t)blockIdx.x*blockDim.x+threadIdx.x;
  const int K=2304;
  size_t tot=(size_t)rows*K;
  if(i>=tot) return;
  int r=(int)(i/K); int k=(int)(i-(size_t)r*K);
  int kk=(k<768)?k:((k<1536)?k-768:k-1536);
  float v=W[(size_t)r*768+kk];
  bf16 h=(bf16)v;
  d[i]=(k<1536)? h : (bf16)(v-(float)h);
}

// ---------------- Wcomb = W_sd2 @ W_sd  (512x512, fp32 exact) ----------------
__global__ __launch_bounds__(256)
void k_wcomb(const float* __restrict__ W2, const float* __restrict__ W1,
             float* __restrict__ out){
  __shared__ float As[64][33];
  __shared__ float Bs[32][65];
  const int tid=threadIdx.x;
  const int i0=blockIdx.x*64, j0=blockIdx.y*64;
  const int tr=(tid>>4)*4, tc=(tid&15)*4;
  float acc[4][4];
  #pragma unroll
  for(int x=0;x<4;++x)
    #pragma unroll
    for(int y=0;y<4;++y) acc[x][y]=0.f;
  for(int k0=0;k0<1024;k0+=32){
    for(int l=tid;l<64*32;l+=256){ int r=l>>5,c=l&31; As[r][c]=W2[(size_t)(i0+r)*1024+k0+c]; }
    for(int l=tid;l<32*64;l+=256){ int r=l>>6,c=l&63; Bs[r][c]=W1[(size_t)(k0+r)*512+j0+c]; }
    __syncthreads();
    #pragma unroll 8
    for(int k=0;k<32;++k){
      float a[4],b[4];
      #pragma unroll
      for(int x=0;x<4;++x){ a[x]=As[tr+x][k]; b[x]=Bs[k][tc+x]; }
      #pragma unroll
      for(int x=0;x<4;++x)
        #pragma unroll
        for(int y=0;y<4;++y) acc[x][y]+=a[x]*b[y];
    }
    __syncthreads();
  }
  #pragma unroll
  for(int x=0;x<4;++x)
    #pragma unroll
    for(int y=0;y<4;++y) out[(size_t)(i0+tr+x)*512+j0+tc+y]=acc[x][y];
}

// ---------------- h_sum: fp32 sum of 4 children (hi+lo), split hi/lo ----------------
__global__ __launch_bounds__(256)
void k_hsum(const bf16* __restrict__ hhi, const bf16* __restrict__ hlo,
            bf16* __restrict__ hs_hi, bf16* __restrict__ hs_lo,
            int start_ch, int lcm1, int P){
  int idx=blockIdx.x*256+threadIdx.x;
  int m=idx>>6;
  if(m>=P) return;
  int c8=(idx&63)*8;
  int cm=m<<2;
  int t=cm>>lcm1, ci=cm-(t<<lcm1);
  const size_t base=((size_t)t*NPT+start_ch+ci)*HD+c8;
  float s[8];
  #pragma unroll
  for(int e=0;e<8;++e) s[e]=0.f;
  #pragma unroll
  for(int ch=0;ch<4;++ch){
    bf16x8 a=*(const bf16x8*)(hhi+base+(size_t)ch*HD);
    bf16x8 b=*(const bf16x8*)(hlo+base+(size_t)ch*HD);
    #pragma unroll
    for(int e=0;e<8;++e) s[e]+=(float)a[e]+(float)b[e];
  }
  bf16x8 oh,ol;
  #pragma unroll
  for(int e=0;e<8;++e){ bf16 hv=(bf16)s[e]; oh[e]=hv; ol[e]=(bf16)(s[e]-(float)hv); }
  *(bf16x8*)(hs_hi+(size_t)m*HD+c8)=oh;
  *(bf16x8*)(hs_lo+(size_t)m*HD+c8)=ol;
}

// ---------------- segment maps ----------------
__device__ __forceinline__ const bf16* segA(int k0, const bf16* fH, const bf16* fL,
                                            const bf16* hH, const bf16* hL,
                                            size_t frow, size_t hrow, int internal){
  if(internal){
    if(k0<768)        return fH+frow+k0;
    else if(k0<1536)  return fL+frow+(k0-768);
    else if(k0<2048)  return hH+hrow+(k0-1536);
    else if(k0<2560)  return hL+hrow+(k0-2048);
    else if(k0<3328)  return fH+frow+(k0-2560);
    else              return hH+hrow+(k0-3328);
  }else{
    if(k0<768)        return fH+frow+k0;
    else if(k0<1536)  return fL+frow+(k0-768);
    else              return fH+frow+(k0-1536);
  }
}

// ================= 128-row m97-style iou GEMM (levels 0..4) =================
// tile: 128 rows x 64 cols x 3 gates, BK=32, global_load_lds staging
__global__ __launch_bounds__(256,2)
void k_iou128(const bf16* __restrict__ fH, const bf16* __restrict__ fL,
              const bf16* __restrict__ hsH, const bf16* __restrict__ hsL,
              const bf16* __restrict__ Wcat, const float* __restrict__ bias,
              const float* __restrict__ csum, bf16* __restrict__ hbuf,
              bf16* __restrict__ hlo, float* __restrict__ cbuf,
              int start_n, int shift, int K, int KB, int internal)
{
  __shared__ bf16 As[128][32];
  __shared__ bf16 Bs[3][64][32];
  const int tid=threadIdx.x;
  const int w=tid>>6, lane=tid&63;
  const int m0=blockIdx.x*128, n0=blockIdx.y*64;

  // A staging rows: instr i in {0,1}: wave-uniform r0=w*16+i*64, lane row = r0+(lane>>2)
  size_t frowA[2], hrowA[2];
  #pragma unroll
  for(int i=0;i<2;++i){
    int r=w*16+i*64+(lane>>2);
    int m=m0+r;
    int t=m>>shift, j=m-(t<<shift);
    frowA[i]=((size_t)t*NPT+start_n+j)*768;
    hrowA[i]=(size_t)m*HD;
  }
  // B staging: instr i in {0,1,2}: f=w*3+i, g=f>>2, r0=(f&3)*16
  size_t brow[3];
  #pragma unroll
  for(int i=0;i<3;++i){
    int f=w*3+i, g=f>>2;
    brow[i]=(size_t)(g*512+n0+(f&3)*16+(lane>>2))*KB;
  }
  const int acol=(lane&3)*8;

  f32x4 acc[3][4][2];
  #pragma unroll
  for(int g=0;g<3;++g)
    #pragma unroll
    for(int mi=0;mi<4;++mi)
      #pragma unroll
      for(int ni=0;ni<2;++ni) acc[g][mi][ni]=(f32x4){0.f,0.f,0.f,0.f};

  const int wr=(w>>1)*64, wc=(w&1)*32;
  const int lr=lane&15, lg=lane>>4;

  for(int k0=0;k0<K;k0+=32){
    #pragma unroll
    for(int i=0;i<2;++i){
      const bf16* gp=segA(k0,fH,fL,hsH,hsL,frowA[i],hrowA[i],internal)+acol;
      gll16(gp,&As[w*16+i*64][0]);
    }
    #pragma unroll
    for(int i=0;i<3;++i){
      int f=w*3+i, g=f>>2;
      gll16(Wcat+brow[i]+k0+acol,&Bs[g][(f&3)*16][0]);
    }
    __syncthreads();
    bf16x8 av[4];
    #pragma unroll
    for(int mi=0;mi<4;++mi) av[mi]=*(bf16x8*)&As[wr+mi*16+lr][lg*8];
    #pragma unroll
    for(int g=0;g<3;++g){
      #pragma unroll
      for(int ni=0;ni<2;++ni){
        bf16x8 bv=*(bf16x8*)&Bs[g][wc+ni*16+lr][lg*8];
        #pragma unroll
        for(int mi=0;mi<4;++mi)
          acc[g][mi][ni]=__builtin_amdgcn_mfma_f32_16x16x32_bf16(av[mi],bv,acc[g][mi][ni],0,0,0);
      }
    }
    __syncthreads();
  }

  #pragma unroll
  for(int mi=0;mi<4;++mi){
    #pragma unroll
    for(int ni=0;ni<2;++ni){
      const int col=n0+wc+ni*16+lr;
      const float bi=bias[col], bo=bias[col+512], bu=bias[col+1024];
      #pragma unroll
      for(int r=0;r<4;++r){
        const int mm=m0+wr+mi*16+lg*4+r;
        float iv=acc[0][mi][ni][r]+bi;
        float ov=acc[1][mi][ni][r]+bo;
        float uv=acc[2][mi][ni][r]+bu;
        float cn=sigm(iv)*tanhf(uv);
        if(internal) cn+=csum[(size_t)mm*HD+col];
        float hn=sigm(ov)*tanhf(cn);
        const int tt=mm>>shift, jj=mm-(tt<<shift);
        const size_t nd=((size_t)tt*NPT+start_n+jj)*HD+col;
        cbuf[nd]=cn;
        bf16 hh=(bf16)hn;
        hbuf[nd]=hh;
        hlo[nd]=(bf16)(hn-(float)hh);
      }
    }
  }
}

// ---------------- old 64-tile iou (kept for level 5, P=64) ----------------
__global__ __launch_bounds__(256)
void k_iou(const bf16* __restrict__ fH, const bf16* __restrict__ fL,
           const bf16* __restrict__ hsH, const bf16* __restrict__ hsL,
           const bf16* __restrict__ Wcat, const float* __restrict__ bias,
           const float* __restrict__ csum, bf16* __restrict__ hbuf,
           bf16* __restrict__ hlo, float* __restrict__ cbuf,
           int start_n, int shift, int K, int KB, int internal)
{
  __shared__ bf16 As[64][40];
  __shared__ bf16 Bs[3][64][40];
  const int tid=threadIdx.x;
  const int m0=blockIdx.x*64, n0=blockIdx.y*64;
  const int srow=tid>>2, skc=(tid&3)*8;
  const int m=m0+srow;
  const int t=m>>shift, j=m-(t<<shift);
  const size_t frow=((size_t)t*NPT+start_n+j)*768;
  const bf16* aFH=fH+frow;
  const bf16* aFL=fL+frow;
  const bf16* aHH=hsH+(size_t)m*HD;
  const bf16* aHL=hsL+(size_t)m*HD;
  const bf16* bp0=Wcat+(size_t)(n0+srow)*KB;
  const bf16* bp1=Wcat+(size_t)(512+n0+srow)*KB;
  const bf16* bp2=Wcat+(size_t)(1024+n0+srow)*KB;

  f32x4 acc[3][2][2];
  #pragma unroll
  for(int g=0;g<3;++g)
    #pragma unroll
    for(int mi=0;mi<2;++mi)
      #pragma unroll
      for(int ni=0;ni<2;++ni) acc[g][mi][ni]=(f32x4){0.f,0.f,0.f,0.f};

  const int w=tid>>6, lane=tid&63;
  const int wr=(w>>1)*32, wc=(w&1)*32;
  const int lr=lane&15, lg=lane>>4;

  for(int k0=0;k0<K;k0+=32){
    const bf16* ap;
    if(internal){
      if(k0<768)        ap=aFH+k0;
      else if(k0<1536)  ap=aFL+(k0-768);
      else if(k0<2048)  ap=aHH+(k0-1536);
      else if(k0<2560)  ap=aHL+(k0-2048);
      else if(k0<3328)  ap=aFH+(k0-2560);
      else              ap=aHH+(k0-3328);
    }else{
      ap=(k0<768)? (aFH+k0) : ((k0<1536)? (aFL+(k0-768)) : (aFH+(k0-1536)));
    }
    *(bf16x8*)&As[srow][skc]=*(const bf16x8*)(ap+skc);
    *(bf16x8*)&Bs[0][srow][skc]=*(const bf16x8*)(bp0+k0+skc);
    *(bf16x8*)&Bs[1][srow][skc]=*(const bf16x8*)(bp1+k0+skc);
    *(bf16x8*)&Bs[2][srow][skc]=*(const bf16x8*)(bp2+k0+skc);
    __syncthreads();
    bf16x8 a0=*(bf16x8*)&As[wr+lr][lg*8];
    bf16x8 a1=*(bf16x8*)&As[wr+16+lr][lg*8];
    #pragma unroll
    for(int g=0;g<3;++g){
      #pragma unroll
      for(int ni=0;ni<2;++ni){
        bf16x8 bv=*(bf16x8*)&Bs[g][wc+ni*16+lr][lg*8];
        acc[g][0][ni]=__builtin_amdgcn_mfma_f32_16x16x32_bf16(a0,bv,acc[g][0][ni],0,0,0);
        acc[g][1][ni]=__builtin_amdgcn_mfma_f32_16x16x32_bf16(a1,bv,acc[g][1][ni],0,0,0);
      }
    }
    __syncthreads();
  }

  #pragma unroll
  for(int mi=0;mi<2;++mi){
    #pragma unroll
    for(int ni=0;ni<2;++ni){
      const int col=n0+wc+ni*16+lr;
      const float bi=bias[col], bo=bias[col+512], bu=bias[col+1024];
      #pragma unroll
      for(int r=0;r<4;++r){
        const int mm=m0+wr+mi*16+lg*4+r;
        float iv=acc[0][mi][ni][r]+bi;
        float ov=acc[1][mi][ni][r]+bo;
        float uv=acc[2][mi][ni][r]+bu;
        float cn=sigm(iv)*tanhf(uv);
        if(internal) cn+=csum[(size_t)mm*HD+col];
        float hn=sigm(ov)*tanhf(cn);
        const int tt=mm>>shift, jj=mm-(tt<<shift);
        const size_t nd=((size_t)tt*NPT+start_n+jj)*HD+col;
        cbuf[nd]=cn;
        bf16 hh=(bf16)hn;
        hbuf[nd]=hh;
        hlo[nd]=(bf16)(hn-(float)hh);
      }
    }
  }
}

// ================= 128x128 m97-style forget-gate GEMM =================
__global__ __launch_bounds__(256,2)
void k_f128(const bf16* __restrict__ fH, const bf16* __restrict__ fL,
            const bf16* __restrict__ hhi, const bf16* __restrict__ hlo,
            const bf16* __restrict__ Wcatf, const float* __restrict__ bias,
            const float* __restrict__ cbuf, float* __restrict__ csum,
            int start_par, int start_ch, int lc)
{
  __shared__ bf16 As[128][32];
  __shared__ bf16 Bs[128][32];
  const int tid=threadIdx.x;
  const int w=tid>>6, lane=tid&63;
  const int e0=blockIdx.x*128, n0=blockIdx.y*128;

  size_t frowA[2], hrowA[2], brow[2];
  #pragma unroll
  for(int i=0;i<2;++i){
    int r=w*16+i*64+(lane>>2);
    int e=e0+r;
    int t=e>>lc, ei=e-(t<<lc);
    frowA[i]=((size_t)t*NPT+start_par+(ei>>2))*768;
    hrowA[i]=((size_t)t*NPT+start_ch+ei)*HD;
    brow[i]=(size_t)(n0+r)*3840;
  }
  const int acol=(lane&3)*8;

  f32x4 acc[4][4];
  #pragma unroll
  for(int mi=0;mi<4;++mi)
    #pragma unroll
    for(int ni=0;ni<4;++ni) acc[mi][ni]=(f32x4){0.f,0.f,0.f,0.f};

  const int wr=(w>>1)*64, wc=(w&1)*64;
  const int lr=lane&15, lg=lane>>4;

  for(int k0=0;k0<3840;k0+=32){
    #pragma unroll
    for(int i=0;i<2;++i){
      const bf16* gp=segA(k0,fH,fL,hhi,hlo,frowA[i],hrowA[i],1)+acol;
      gll16(gp,&As[w*16+i*64][0]);
      gll16(Wcatf+brow[i]+k0+acol,&Bs[w*16+i*64][0]);
    }
    __syncthreads();
    bf16x8 av[4];
    #pragma unroll
    for(int mi=0;mi<4;++mi) av[mi]=*(bf16x8*)&As[wr+mi*16+lr][lg*8];
    #pragma unroll
    for(int ni=0;ni<4;++ni){
      bf16x8 bv=*(bf16x8*)&Bs[wc+ni*16+lr][lg*8];
      #pragma unroll
      for(int mi=0;mi<4;++mi)
        acc[mi][ni]=__builtin_amdgcn_mfma_f32_16x16x32_bf16(av[mi],bv,acc[mi][ni],0,0,0);
    }
    __syncthreads();
  }

  #pragma unroll
  for(int mi=0;mi<4;++mi){
    const int ebase=e0+wr+mi*16+lg*4;
    const int tt=ebase>>lc, eib=ebase-(tt<<lc);
    #pragma unroll
    for(int ni=0;ni<4;++ni){
      const int col=n0+wc+ni*16+lr;
      const float bb=bias[col];
      const size_t chbase=((size_t)tt*NPT+start_ch+eib)*HD+col;
      float s=0.f;
      #pragma unroll
      for(int r=0;r<4;++r){
        float fv=sigm(acc[mi][ni][r]+bb);
        s+=fv*cbuf[chbase+(size_t)r*HD];
      }
      csum[((size_t)(ebase>>2))*HD+col]=s;
    }
  }
}

// ================= 128x128 m97-style stance GEMM (split precision) =================
__global__ __launch_bounds__(256,2)
void k_stance128(const bf16* __restrict__ Ahi, const bf16* __restrict__ Alo,
                 const bf16* __restrict__ Bhi, const bf16* __restrict__ Blo,
                 float* __restrict__ C, int Mtot)
{
  __shared__ bf16 AsH[128][32];
  __shared__ bf16 AsL[128][32];
  __shared__ bf16 BsH[128][32];
  __shared__ bf16 BsL[128][32];
  const int tid=threadIdx.x;
  const int w=tid>>6, lane=tid&63;
  const int m0=blockIdx.x*128, n0=blockIdx.y*128;

  size_t arow[2], browi[2];
  #pragma unroll
  for(int i=0;i<2;++i){
    int r=w*16+i*64+(lane>>2);
    int m=m0+r; if(m>Mtot-1) m=Mtot-1;
    arow[i]=(size_t)m*HD;
    browi[i]=(size_t)(n0+r)*HD;
  }
  const int acol=(lane&3)*8;

  f32x4 acc[4][4];
  #pragma unroll
  for(int mi=0;mi<4;++mi)
    #pragma unroll
    for(int ni=0;ni<4;++ni) acc[mi][ni]=(f32x4){0.f,0.f,0.f,0.f};

  const int wr=(w>>1)*64, wc=(w&1)*64;
  const int lr=lane&15, lg=lane>>4;

  for(int k0=0;k0<HD;k0+=32){
    #pragma unroll
    for(int i=0;i<2;++i){
      gll16(Ahi+arow[i]+k0+acol,&AsH[w*16+i*64][0]);
      gll16(Alo+arow[i]+k0+acol,&AsL[w*16+i*64][0]);
      gll16(Bhi+browi[i]+k0+acol,&BsH[w*16+i*64][0]);
      gll16(Blo+browi[i]+k0+acol,&BsL[w*16+i*64][0]);
    }
    __syncthreads();
    bf16x8 avh[4], avl[4];
    #pragma unroll
    for(int mi=0;mi<4;++mi){
      avh[mi]=*(bf16x8*)&AsH[wr+mi*16+lr][lg*8];
      avl[mi]=*(bf16x8*)&AsL[wr+mi*16+lr][lg*8];
    }
    #pragma unroll
    for(int ni=0;ni<4;++ni){
      bf16x8 bvh=*(bf16x8*)&BsH[wc+ni*16+lr][lg*8];
      bf16x8 bvl=*(bf16x8*)&BsL[wc+ni*16+lr][lg*8];
      #pragma unroll
      for(int mi=0;mi<4;++mi){
        acc[mi][ni]=__builtin_amdgcn_mfma_f32_16x16x32_bf16(avh[mi],bvh,acc[mi][ni],0,0,0);
        acc[mi][ni]=__builtin_amdgcn_mfma_f32_16x16x32_bf16(avl[mi],bvh,acc[mi][ni],0,0,0);
        acc[mi][ni]=__builtin_amdgcn_mfma_f32_16x16x32_bf16(avh[mi],bvl,acc[mi][ni],0,0,0);
      }
    }
    __syncthreads();
  }

  #pragma unroll
  for(int mi=0;mi<4;++mi){
    #pragma unroll
    for(int ni=0;ni<4;++ni){
      const int col=n0+wc+ni*16+lr;
      #pragma unroll
      for(int r=0;r<4;++r){
        const int mm=m0+wr+mi*16+lg*4+r;
        if(mm<Mtot){
          const size_t idx=(size_t)mm*HD+col;
          C[idx]=acc[mi][ni][r]+(float)Ahi[idx]+(float)Alo[idx];
        }
      }
    }
  }
}

// ---------------- final: y = h_st @ W_sf^T, LayerNorm(4), softmax (all fp32) ----------------
__global__ __launch_bounds__(256)
void k_final(const float* __restrict__ hst, const float* __restrict__ Wsf,
             const float* __restrict__ gamma, const float* __restrict__ beta,
             float* __restrict__ out0, int Nn)
{
  const int gtid=blockIdx.x*256+threadIdx.x;
  const int node=gtid>>6, lane=gtid&63;
  if(node>=Nn) return;
  const float* hp=hst+(size_t)node*HD+lane*8;
  float hf[8];
  #pragma unroll
  for(int e=0;e<8;++e) hf[e]=hp[e];
  float y[4];
  #pragma unroll
  for(int jj=0;jj<4;++jj){
    const float* wp=Wsf+jj*HD+lane*8;
    float s=0.f;
    #pragma unroll
    for(int e=0;e<8;++e) s+=hf[e]*wp[e];
    #pragma unroll
    for(int off=32;off>=1;off>>=1) s+=__shfl_xor(s,off,64);
    y[jj]=s;
  }
  if(lane==0){
    float mu=0.25f*(y[0]+y[1]+y[2]+y[3]);
    float var=0.f;
    #pragma unroll
    for(int jj=0;jj<4;++jj){ float d=y[jj]-mu; var+=d*d; }
    var*=0.25f;
    float rs=rsqrtf(var+1e-6f);
    float z[4], zmax=-1e30f;
    #pragma unroll
    for(int jj=0;jj<4;++jj){ z[jj]=(y[jj]-mu)*rs*gamma[jj]+beta[jj]; zmax=fmaxf(zmax,z[jj]); }
    float es=0.f;
    #pragma unroll
    for(int jj=0;jj<4;++jj){ z[jj]=__expf(z[jj]-zmax); es+=z[jj]; }
    float inv=1.f/es;
    #pragma unroll
    for(int jj=0;jj<4;++jj) out0[(size_t)node*4+jj]=z[jj]*inv;
  }
}

// ---------------- root head ----------------
__global__ __launch_bounds__(256)
void k_root(const bf16* __restrict__ hhi, const bf16* __restrict__ hlo,
            const float* __restrict__ Wff, float* __restrict__ out1)
{
  const int gtid=blockIdx.x*256+threadIdx.x;
  const int tt=gtid>>6, lane=gtid&63;
  if(tt>=64) return;
  const size_t base=((size_t)tt*NPT+1364)*HD+lane*8;
  bf16x8 hv=*(const bf16x8*)(hhi+base);
  bf16x8 lv=*(const bf16x8*)(hlo+base);
  float hf[8];
  #pragma unroll
  for(int e=0;e<8;++e) hf[e]=(float)hv[e]+(float)lv[e];
  float y[4];
  #pragma unroll
  for(int jj=0;jj<4;++jj){
    const float* wp=Wff+jj*HD+lane*8;
    float s=0.f;
    #pragma unroll
    for(int e=0;e<8;++e) s+=hf[e]*wp[e];
    #pragma unroll
    for(int off=32;off>=1;off>>=1) s+=__shfl_xor(s,off,64);
    y[jj]=s;
  }
  if(lane==0){
    float zmax=fmaxf(fmaxf(y[0],y[1]),fmaxf(y[2],y[3]));
    float es=0.f, z[4];
    #pragma unroll
    for(int jj=0;jj<4;++jj){ z[jj]=__expf(y[jj]-zmax); es+=z[jj]; }
    float inv=1.f/es;
    #pragma unroll
    for(int jj=0;jj<4;++jj) out1[(size_t)tt*4+jj]=z[jj]*inv;
  }
}

extern "C" void kernel_launch(void* const* d_in, const int* in_sizes, int n_in,
                              void* d_out, int out_size, void* d_ws, size_t ws_size,
                              hipStream_t stream)
{
  const float* features=(const float*)d_in[0];
  const float* W_iou=(const float*)d_in[6];
  const float* b_iou=(const float*)d_in[7];
  const float* U_iou=(const float*)d_in[8];
  const float* W_f  =(const float*)d_in[9];
  const float* b_f  =(const float*)d_in[10];
  const float* U_f  =(const float*)d_in[11];
  const float* W_ff =(const float*)d_in[12];
  const float* W_sd =(const float*)d_in[13];
  const float* W_sd2=(const float*)d_in[14];
  const float* W_sf =(const float*)d_in[15];
  const float* ln_g =(const float*)d_in[16];
  const float* ln_b =(const float*)d_in[17];

  const int N=in_sizes[0]/768;   // 87360
  const int T=N/NPT;             // 64

  float* out0=(float*)d_out;
  float* out1=out0+(size_t)N*4;
  float* cbuf=out1+(size_t)T*4;  // c output region, used as live c-state

  char* p=(char*)d_ws;
  auto alloc=[&](size_t bytes){ char* r=p; p+=((bytes+255)&~(size_t)255); return r; };
  // region A — dead after the tree pass; reused for fp32 hst
  char*  regionA=p;
  bf16*  f_hi =(bf16*) alloc((size_t)N*768*2);
  bf16*  f_lo =(bf16*) alloc((size_t)N*768*2);
  // persistent region
  bf16*  hs_hi=(bf16*) alloc((size_t)16384*HD*2);
  bf16*  hs_lo=(bf16*) alloc((size_t)16384*HD*2);
  float* csum =(float*)alloc((size_t)16384*HD*4);
  bf16*  h_hi =(bf16*) alloc((size_t)N*HD*2);
  bf16*  h_lo =(bf16*) alloc((size_t)N*HD*2);
  bf16*  WcatI=(bf16*) alloc((size_t)1536*3840*2);
  bf16*  WlfI =(bf16*) alloc((size_t)1536*2304*2);
  bf16*  WcatF=(bf16*) alloc((size_t)512*3840*2);
  float* Wcomb=(float*)alloc((size_t)512*512*4);
  bf16*  Wc_hi=(bf16*) alloc((size_t)512*512*2);
  bf16*  Wc_lo=(bf16*) alloc((size_t)512*512*2);
  float* hst  =(float*)regionA;

  // conversions / weight prep
  { size_t n=(size_t)N*768;     k_split<<<(int)((n+255)/256),256,0,stream>>>(features,f_hi,f_lo,n); }
  { size_t n=(size_t)1536*3840; k_concatHL<<<(int)((n+255)/256),256,0,stream>>>(W_iou,U_iou,WcatI,1536); }
  { size_t n=(size_t)1536*2304; k_concatLeaf<<<(int)((n+255)/256),256,0,stream>>>(W_iou,WlfI,1536); }
  { size_t n=(size_t)512*3840;  k_concatHL<<<(int)((n+255)/256),256,0,stream>>>(W_f,U_f,WcatF,512); }
  { dim3 g(8,8); k_wcomb<<<g,256,0,stream>>>(W_sd2,W_sd,Wcomb); }
  { size_t n=(size_t)512*512;   k_split<<<(int)((n+255)/256),256,0,stream>>>(Wcomb,Wc_hi,Wc_lo,n); }

  static const int starts[6]={0,1024,1280,1344,1360,1364};
  static const int csh[6]  ={10,8,6,4,2,0};
  static const int counts[6]={1024,256,64,16,4,1};

  // level 0 (leaves): K=2304, 128-row tiles
  { dim3 g((T*1024)/128, 8);
    k_iou128<<<g,256,0,stream>>>(f_hi,f_lo,hs_hi,hs_lo,WlfI,b_iou,csum,h_hi,h_lo,cbuf,0,10,2304,2304,0); }

  for(int n=1;n<6;++n){
    int P=T*counts[n], E=T*counts[n-1];
    { int th=P*64; k_hsum<<<(th+255)/256,256,0,stream>>>(h_hi,h_lo,hs_hi,hs_lo,starts[n-1],csh[n-1],P); }
    { dim3 g(E/128,4);
      k_f128<<<g,256,0,stream>>>(f_hi,f_lo,h_hi,h_lo,WcatF,b_f,cbuf,csum,starts[n],starts[n-1],csh[n-1]); }
    if(P>=128){
      dim3 g(P/128,8);
      k_iou128<<<g,256,0,stream>>>(f_hi,f_lo,hs_hi,hs_lo,WcatI,b_iou,csum,h_hi,h_lo,cbuf,starts[n],csh[n],3840,3840,1);
    }else{
      dim3 g(P/64,8);
      k_iou<<<g,256,0,stream>>>(f_hi,f_lo,hs_hi,hs_lo,WcatI,b_iou,csum,h_hi,h_lo,cbuf,starts[n],csh[n],3840,3840,1);
    }
  }

  // stance: h_st = h @ Wcomb^T + h  (split-precision, fp32 out)
  { dim3 g((N+127)/128, 4);
    k_stance128<<<g,256,0,stream>>>(h_hi,h_lo,Wc_hi,Wc_lo,hst,N); }

  // heads
  { int th=N*64; k_final<<<(th+255)/256,256,0,stream>>>(hst,W_sf,ln_g,ln_b,out0,N); }
  { k_root<<<16,256,0,stream>>>(h_hi,h_lo,W_ff,out1); }
}

// Round 6
// 2382.708 us; speedup vs baseline: 1.4458x; 1.2589x over previous
//
#include <hip/hip_runtime.h>
#include <hip/hip_bf16.h>
#include <math.h>

typedef __bf16 bf16;
typedef bf16 bf16x8 __attribute__((ext_vector_type(8)));
typedef float f32x4 __attribute__((ext_vector_type(4)));

#define NPT 1365
#define HD 512

__device__ __forceinline__ float sigm(float x){ return 1.0f/(1.0f+__expf(-x)); }

__device__ __forceinline__ void gll16(const void* g, void* l){
  __builtin_amdgcn_global_load_lds((const __attribute__((address_space(1))) void*)g,
                                   (__attribute__((address_space(3))) void*)l, 16, 0, 0);
}

// ---------------- split fp32 -> bf16 hi/lo ----------------
__global__ void k_split(const float* __restrict__ s, bf16* __restrict__ hi,
                        bf16* __restrict__ lo, size_t n){
  size_t i=(size_t)blockIdx.x*blockDim.x+threadIdx.x;
  if(i<n){ float v=s[i]; bf16 h=(bf16)v; hi[i]=h; lo[i]=(bf16)(v-(float)h); }
}

// ---------------- weight concat K=2560: [Whi(768)|Uhi(512)|Wlo(768)|Ulo(512)] ----------------
__global__ void k_concat2560(const float* __restrict__ W, const float* __restrict__ U,
                             bf16* __restrict__ d, int rows){
  size_t i=(size_t)blockIdx.x*blockDim.x+threadIdx.x;
  const int K=2560;
  size_t tot=(size_t)rows*K;
  if(i>=tot) return;
  int r=(int)(i/K); int k=(int)(i-(size_t)r*K);
  float v; int lo=0;
  if(k<768)        v=W[(size_t)r*768+k];
  else if(k<1280)  v=U[(size_t)r*512+(k-768)];
  else if(k<2048){ v=W[(size_t)r*768+(k-1280)]; lo=1; }
  else           { v=U[(size_t)r*512+(k-2048)]; lo=1; }
  bf16 h=(bf16)v;
  d[i]= lo ? (bf16)(v-(float)h) : h;
}

// ---------------- old-layout concat K=3840 (kept for level-5 64-tile iou) ----------------
__global__ void k_concatHL(const float* __restrict__ W, const float* __restrict__ U,
                           bf16* __restrict__ d, int rows){
  size_t i=(size_t)blockIdx.x*blockDim.x+threadIdx.x;
  const int K=3840;
  size_t tot=(size_t)rows*K;
  if(i>=tot) return;
  int r=(int)(i/K); int k=(int)(i-(size_t)r*K);
  float v; int lo=0;
  if(k<768)        v=W[(size_t)r*768+k];
  else if(k<1536)  v=W[(size_t)r*768+(k-768)];
  else if(k<2048)  v=U[(size_t)r*512+(k-1536)];
  else if(k<2560)  v=U[(size_t)r*512+(k-2048)];
  else if(k<3328){ v=W[(size_t)r*768+(k-2560)]; lo=1; }
  else           { v=U[(size_t)r*512+(k-3328)]; lo=1; }
  bf16 h=(bf16)v;
  d[i]= lo ? (bf16)(v-(float)h) : h;
}

// ---------------- Wcomb = W_sd2 @ W_sd  (512x512, fp32 exact) ----------------
__global__ __launch_bounds__(256)
void k_wcomb(const float* __restrict__ W2, const float* __restrict__ W1,
             float* __restrict__ out){
  __shared__ float As[64][33];
  __shared__ float Bs[32][65];
  const int tid=threadIdx.x;
  const int i0=blockIdx.x*64, j0=blockIdx.y*64;
  const int tr=(tid>>4)*4, tc=(tid&15)*4;
  float acc[4][4];
  #pragma unroll
  for(int x=0;x<4;++x)
    #pragma unroll
    for(int y=0;y<4;++y) acc[x][y]=0.f;
  for(int k0=0;k0<1024;k0+=32){
    for(int l=tid;l<64*32;l+=256){ int r=l>>5,c=l&31; As[r][c]=W2[(size_t)(i0+r)*1024+k0+c]; }
    for(int l=tid;l<32*64;l+=256){ int r=l>>6,c=l&63; Bs[r][c]=W1[(size_t)(k0+r)*512+j0+c]; }
    __syncthreads();
    #pragma unroll 8
    for(int k=0;k<32;++k){
      float a[4],b[4];
      #pragma unroll
      for(int x=0;x<4;++x){ a[x]=As[tr+x][k]; b[x]=Bs[k][tc+x]; }
      #pragma unroll
      for(int x=0;x<4;++x)
        #pragma unroll
        for(int y=0;y<4;++y) acc[x][y]+=a[x]*b[y];
    }
    __syncthreads();
  }
  #pragma unroll
  for(int x=0;x<4;++x)
    #pragma unroll
    for(int y=0;y<4;++y) out[(size_t)(i0+tr+x)*512+j0+tc+y]=acc[x][y];
}

// ---------------- Wy[j,c] = Wsf[j,c] + sum_d Wsf[j,d]*Wcomb[d,c]  (4x512) ----------------
__global__ void k_wy(const float* __restrict__ Wsf, const float* __restrict__ Wcomb,
                     float* __restrict__ Wy){
  int idx=blockIdx.x*256+threadIdx.x;
  if(idx>=2048) return;
  int j=idx>>9, c=idx&511;
  float s=Wsf[j*512+c];
  for(int d=0;d<512;++d) s+=Wsf[j*512+d]*Wcomb[(size_t)d*512+c];
  Wy[(size_t)j*512+c]=s;
}

// ---------------- h_sum: fp32 sum of 4 children (hi+lo), split hi/lo ----------------
__global__ __launch_bounds__(256)
void k_hsum(const bf16* __restrict__ hhi, const bf16* __restrict__ hlo,
            bf16* __restrict__ hs_hi, bf16* __restrict__ hs_lo,
            int start_ch, int lcm1, int P){
  int idx=blockIdx.x*256+threadIdx.x;
  int m=idx>>6;
  if(m>=P) return;
  int c8=(idx&63)*8;
  int cm=m<<2;
  int t=cm>>lcm1, ci=cm-(t<<lcm1);
  const size_t base=((size_t)t*NPT+start_ch+ci)*HD+c8;
  float s[8];
  #pragma unroll
  for(int e=0;e<8;++e) s[e]=0.f;
  #pragma unroll
  for(int ch=0;ch<4;++ch){
    bf16x8 a=*(const bf16x8*)(hhi+base+(size_t)ch*HD);
    bf16x8 b=*(const bf16x8*)(hlo+base+(size_t)ch*HD);
    #pragma unroll
    for(int e=0;e<8;++e) s[e]+=(float)a[e]+(float)b[e];
  }
  bf16x8 oh,ol;
  #pragma unroll
  for(int e=0;e<8;++e){ bf16 hv=(bf16)s[e]; oh[e]=hv; ol[e]=(bf16)(s[e]-(float)hv); }
  *(bf16x8*)(hs_hi+(size_t)m*HD+c8)=oh;
  *(bf16x8*)(hs_lo+(size_t)m*HD+c8)=ol;
}

// ================= iou GEMM, 128 rows x 64 cols x 3 gates, K-dedup regions =================
// weight layout per row (K=2560): [Whi 0..768 | Uhi 768..1280 | Wlo 1280..2048 | Ulo 2048..2560]
// regions: fH(768,dual Whi+Wlo) fL(768,Whi) [internal: hH(512,dual Uhi+Ulo) hL(512,Uhi)]
__global__ __launch_bounds__(256,2)
void k_iou128(const bf16* __restrict__ fH, const bf16* __restrict__ fL,
              const bf16* __restrict__ hsH, const bf16* __restrict__ hsL,
              const bf16* __restrict__ Wcat, const float* __restrict__ bias,
              const float* __restrict__ csum, bf16* __restrict__ hbuf,
              bf16* __restrict__ hlo, float* __restrict__ cbuf,
              int start_n, int shift, int internal)
{
  __shared__ bf16 As[128][32];
  __shared__ bf16 Bs[6][64][32];
  const int tid=threadIdx.x;
  const int w=tid>>6, lane=tid&63;
  const int m0=blockIdx.x*128, n0=blockIdx.y*64;

  size_t frowA[2], hrowA[2];
  #pragma unroll
  for(int i=0;i<2;++i){
    int r=w*16+i*64+(lane>>2);
    int m=m0+r;
    int t=m>>shift, j=m-(t<<shift);
    frowA[i]=((size_t)t*NPT+start_n+j)*768;
    hrowA[i]=(size_t)m*HD;
  }
  const bf16* bPtr[6];
  #pragma unroll
  for(int i=0;i<6;++i){
    int row=(i>>1)*512 + n0 + w*16 + (lane>>2);
    bPtr[i]=Wcat+(size_t)row*2560;
  }
  const int acol=(lane&3)*8;

  f32x4 acc[3][4][2];
  #pragma unroll
  for(int g=0;g<3;++g)
    #pragma unroll
    for(int mi=0;mi<4;++mi)
      #pragma unroll
      for(int ni=0;ni<2;++ni) acc[g][mi][ni]=(f32x4){0.f,0.f,0.f,0.f};

  const int wr=(w>>1)*64, wc=(w&1)*32;
  const int lr=lane&15, lg=lane>>4;

  auto STEP=[&](const bf16* a0, const bf16* a1, int offH, int offL, bool dual){
    gll16(a0,&As[w*16][0]);
    gll16(a1,&As[w*16+64][0]);
    if(dual){
      #pragma unroll
      for(int i=0;i<6;++i)
        gll16(bPtr[i]+((i&1)?offL:offH)+acol,&Bs[i][w*16][0]);
    }else{
      #pragma unroll
      for(int i=0;i<3;++i)
        gll16(bPtr[2*i]+offH+acol,&Bs[2*i][w*16][0]);
    }
    __syncthreads();
    bf16x8 av[4];
    #pragma unroll
    for(int mi=0;mi<4;++mi) av[mi]=*(bf16x8*)&As[wr+mi*16+lr][lg*8];
    #pragma unroll
    for(int g=0;g<3;++g){
      #pragma unroll
      for(int ni=0;ni<2;++ni){
        bf16x8 bvh=*(bf16x8*)&Bs[2*g][wc+ni*16+lr][lg*8];
        #pragma unroll
        for(int mi=0;mi<4;++mi)
          acc[g][mi][ni]=__builtin_amdgcn_mfma_f32_16x16x32_bf16(av[mi],bvh,acc[g][mi][ni],0,0,0);
        if(dual){
          bf16x8 bvl=*(bf16x8*)&Bs[2*g+1][wc+ni*16+lr][lg*8];
          #pragma unroll
          for(int mi=0;mi<4;++mi)
            acc[g][mi][ni]=__builtin_amdgcn_mfma_f32_16x16x32_bf16(av[mi],bvl,acc[g][mi][ni],0,0,0);
        }
      }
    }
    __syncthreads();
  };

  for(int s=0;s<24;++s){ int kk=s<<5;
    STEP(fH+frowA[0]+kk+acol, fH+frowA[1]+kk+acol, kk, 1280+kk, true); }
  for(int s=0;s<24;++s){ int kk=s<<5;
    STEP(fL+frowA[0]+kk+acol, fL+frowA[1]+kk+acol, kk, 0, false); }
  if(internal){
    for(int s=0;s<16;++s){ int kk=s<<5;
      STEP(hsH+hrowA[0]+kk+acol, hsH+hrowA[1]+kk+acol, 768+kk, 2048+kk, true); }
    for(int s=0;s<16;++s){ int kk=s<<5;
      STEP(hsL+hrowA[0]+kk+acol, hsL+hrowA[1]+kk+acol, 768+kk, 0, false); }
  }

  #pragma unroll
  for(int mi=0;mi<4;++mi){
    #pragma unroll
    for(int ni=0;ni<2;++ni){
      const int col=n0+wc+ni*16+lr;
      const float bi=bias[col], bo=bias[col+512], bu=bias[col+1024];
      #pragma unroll
      for(int r=0;r<4;++r){
        const int mm=m0+wr+mi*16+lg*4+r;
        float iv=acc[0][mi][ni][r]+bi;
        float ov=acc[1][mi][ni][r]+bo;
        float uv=acc[2][mi][ni][r]+bu;
        float cn=sigm(iv)*tanhf(uv);
        if(internal) cn+=csum[(size_t)mm*HD+col];
        float hn=sigm(ov)*tanhf(cn);
        const int tt=mm>>shift, jj=mm-(tt<<shift);
        const size_t nd=((size_t)tt*NPT+start_n+jj)*HD+col;
        cbuf[nd]=cn;
        bf16 hh=(bf16)hn;
        hbuf[nd]=hh;
        hlo[nd]=(bf16)(hn-(float)hh);
      }
    }
  }
}

// ---------------- old 64-tile iou (level 5 only, P=64; old K=3840 layout) ----------------
__global__ __launch_bounds__(256)
void k_iou(const bf16* __restrict__ fH, const bf16* __restrict__ fL,
           const bf16* __restrict__ hsH, const bf16* __restrict__ hsL,
           const bf16* __restrict__ Wcat, const float* __restrict__ bias,
           const float* __restrict__ csum, bf16* __restrict__ hbuf,
           bf16* __restrict__ hlo, float* __restrict__ cbuf,
           int start_n, int shift, int K, int KB, int internal)
{
  __shared__ bf16 As[64][40];
  __shared__ bf16 Bs[3][64][40];
  const int tid=threadIdx.x;
  const int m0=blockIdx.x*64, n0=blockIdx.y*64;
  const int srow=tid>>2, skc=(tid&3)*8;
  const int m=m0+srow;
  const int t=m>>shift, j=m-(t<<shift);
  const size_t frow=((size_t)t*NPT+start_n+j)*768;
  const bf16* aFH=fH+frow;
  const bf16* aFL=fL+frow;
  const bf16* aHH=hsH+(size_t)m*HD;
  const bf16* aHL=hsL+(size_t)m*HD;
  const bf16* bp0=Wcat+(size_t)(n0+srow)*KB;
  const bf16* bp1=Wcat+(size_t)(512+n0+srow)*KB;
  const bf16* bp2=Wcat+(size_t)(1024+n0+srow)*KB;

  f32x4 acc[3][2][2];
  #pragma unroll
  for(int g=0;g<3;++g)
    #pragma unroll
    for(int mi=0;mi<2;++mi)
      #pragma unroll
      for(int ni=0;ni<2;++ni) acc[g][mi][ni]=(f32x4){0.f,0.f,0.f,0.f};

  const int w=tid>>6, lane=tid&63;
  const int wr=(w>>1)*32, wc=(w&1)*32;
  const int lr=lane&15, lg=lane>>4;

  for(int k0=0;k0<K;k0+=32){
    const bf16* ap;
    if(internal){
      if(k0<768)        ap=aFH+k0;
      else if(k0<1536)  ap=aFL+(k0-768);
      else if(k0<2048)  ap=aHH+(k0-1536);
      else if(k0<2560)  ap=aHL+(k0-2048);
      else if(k0<3328)  ap=aFH+(k0-2560);
      else              ap=aHH+(k0-3328);
    }else{
      ap=(k0<768)? (aFH+k0) : ((k0<1536)? (aFL+(k0-768)) : (aFH+(k0-1536)));
    }
    *(bf16x8*)&As[srow][skc]=*(const bf16x8*)(ap+skc);
    *(bf16x8*)&Bs[0][srow][skc]=*(const bf16x8*)(bp0+k0+skc);
    *(bf16x8*)&Bs[1][srow][skc]=*(const bf16x8*)(bp1+k0+skc);
    *(bf16x8*)&Bs[2][srow][skc]=*(const bf16x8*)(bp2+k0+skc);
    __syncthreads();
    bf16x8 a0=*(bf16x8*)&As[wr+lr][lg*8];
    bf16x8 a1=*(bf16x8*)&As[wr+16+lr][lg*8];
    #pragma unroll
    for(int g=0;g<3;++g){
      #pragma unroll
      for(int ni=0;ni<2;++ni){
        bf16x8 bv=*(bf16x8*)&Bs[g][wc+ni*16+lr][lg*8];
        acc[g][0][ni]=__builtin_amdgcn_mfma_f32_16x16x32_bf16(a0,bv,acc[g][0][ni],0,0,0);
        acc[g][1][ni]=__builtin_amdgcn_mfma_f32_16x16x32_bf16(a1,bv,acc[g][1][ni],0,0,0);
      }
    }
    __syncthreads();
  }

  #pragma unroll
  for(int mi=0;mi<2;++mi){
    #pragma unroll
    for(int ni=0;ni<2;++ni){
      const int col=n0+wc+ni*16+lr;
      const float bi=bias[col], bo=bias[col+512], bu=bias[col+1024];
      #pragma unroll
      for(int r=0;r<4;++r){
        const int mm=m0+wr+mi*16+lg*4+r;
        float iv=acc[0][mi][ni][r]+bi;
        float ov=acc[1][mi][ni][r]+bo;
        float uv=acc[2][mi][ni][r]+bu;
        float cn=sigm(iv)*tanhf(uv);
        if(internal) cn+=csum[(size_t)mm*HD+col];
        float hn=sigm(ov)*tanhf(cn);
        const int tt=mm>>shift, jj=mm-(tt<<shift);
        const size_t nd=((size_t)tt*NPT+start_n+jj)*HD+col;
        cbuf[nd]=cn;
        bf16 hh=(bf16)hn;
        hbuf[nd]=hh;
        hlo[nd]=(bf16)(hn-(float)hh);
      }
    }
  }
}

// ================= forget-gate GEMM 128x128, K-dedup regions =================
__global__ __launch_bounds__(256,2)
void k_f128(const bf16* __restrict__ fH, const bf16* __restrict__ fL,
            const bf16* __restrict__ hhi, const bf16* __restrict__ hlo,
            const bf16* __restrict__ Wcatf, const float* __restrict__ bias,
            const float* __restrict__ cbuf, float* __restrict__ csum,
            int start_par, int start_ch, int lc)
{
  __shared__ bf16 As[128][32];
  __shared__ bf16 BsH[128][32];
  __shared__ bf16 BsL[128][32];
  const int tid=threadIdx.x;
  const int w=tid>>6, lane=tid&63;
  const int e0=blockIdx.x*128, n0=blockIdx.y*128;

  size_t frowA[2], hrowA[2];
  #pragma unroll
  for(int i=0;i<2;++i){
    int r=w*16+i*64+(lane>>2);
    int e=e0+r;
    int t=e>>lc, ei=e-(t<<lc);
    frowA[i]=((size_t)t*NPT+start_par+(ei>>2))*768;
    hrowA[i]=((size_t)t*NPT+start_ch+ei)*HD;
  }
  const bf16* bPtr[2];
  #pragma unroll
  for(int i=0;i<2;++i){
    int row=n0+(w*2+i)*16+(lane>>2);
    bPtr[i]=Wcatf+(size_t)row*2560;
  }
  const int acol=(lane&3)*8;

  f32x4 acc[4][4];
  #pragma unroll
  for(int mi=0;mi<4;++mi)
    #pragma unroll
    for(int ni=0;ni<4;++ni) acc[mi][ni]=(f32x4){0.f,0.f,0.f,0.f};

  const int wr=(w>>1)*64, wc=(w&1)*64;
  const int lr=lane&15, lg=lane>>4;

  auto STEP=[&](const bf16* a0, const bf16* a1, int offH, int offL, bool dual){
    gll16(a0,&As[w*16][0]);
    gll16(a1,&As[w*16+64][0]);
    #pragma unroll
    for(int i=0;i<2;++i) gll16(bPtr[i]+offH+acol,&BsH[(w*2+i)*16][0]);
    if(dual){
      #pragma unroll
      for(int i=0;i<2;++i) gll16(bPtr[i]+offL+acol,&BsL[(w*2+i)*16][0]);
    }
    __syncthreads();
    bf16x8 av[4];
    #pragma unroll
    for(int mi=0;mi<4;++mi) av[mi]=*(bf16x8*)&As[wr+mi*16+lr][lg*8];
    #pragma unroll
    for(int ni=0;ni<4;++ni){
      bf16x8 bvh=*(bf16x8*)&BsH[wc+ni*16+lr][lg*8];
      #pragma unroll
      for(int mi=0;mi<4;++mi)
        acc[mi][ni]=__builtin_amdgcn_mfma_f32_16x16x32_bf16(av[mi],bvh,acc[mi][ni],0,0,0);
      if(dual){
        bf16x8 bvl=*(bf16x8*)&BsL[wc+ni*16+lr][lg*8];
        #pragma unroll
        for(int mi=0;mi<4;++mi)
          acc[mi][ni]=__builtin_amdgcn_mfma_f32_16x16x32_bf16(av[mi],bvl,acc[mi][ni],0,0,0);
      }
    }
    __syncthreads();
  };

  for(int s=0;s<24;++s){ int kk=s<<5;
    STEP(fH+frowA[0]+kk+acol, fH+frowA[1]+kk+acol, kk, 1280+kk, true); }
  for(int s=0;s<24;++s){ int kk=s<<5;
    STEP(fL+frowA[0]+kk+acol, fL+frowA[1]+kk+acol, kk, 0, false); }
  for(int s=0;s<16;++s){ int kk=s<<5;
    STEP(hhi+hrowA[0]+kk+acol, hhi+hrowA[1]+kk+acol, 768+kk, 2048+kk, true); }
  for(int s=0;s<16;++s){ int kk=s<<5;
    STEP(hlo+hrowA[0]+kk+acol, hlo+hrowA[1]+kk+acol, 768+kk, 0, false); }

  #pragma unroll
  for(int mi=0;mi<4;++mi){
    const int ebase=e0+wr+mi*16+lg*4;
    const int tt=ebase>>lc, eib=ebase-(tt<<lc);
    #pragma unroll
    for(int ni=0;ni<4;++ni){
      const int col=n0+wc+ni*16+lr;
      const float bb=bias[col];
      const size_t chbase=((size_t)tt*NPT+start_ch+eib)*HD+col;
      float s=0.f;
      #pragma unroll
      for(int r=0;r<4;++r){
        float fv=sigm(acc[mi][ni][r]+bb);
        s+=fv*cbuf[chbase+(size_t)r*HD];
      }
      csum[((size_t)(ebase>>2))*HD+col]=s;
    }
  }
}

// ---------------- final head: y = (h_hi+h_lo) @ Wy^T, LayerNorm(4), softmax ----------------
__global__ __launch_bounds__(256)
void k_final2(const bf16* __restrict__ hhi, const bf16* __restrict__ hlo,
              const float* __restrict__ Wy, const float* __restrict__ gamma,
              const float* __restrict__ beta, float* __restrict__ out0, int Nn)
{
  const int gtid=blockIdx.x*256+threadIdx.x;
  const int node=gtid>>6, lane=gtid&63;
  if(node>=Nn) return;
  const size_t base=(size_t)node*HD+lane*8;
  bf16x8 hv=*(const bf16x8*)(hhi+base);
  bf16x8 lv=*(const bf16x8*)(hlo+base);
  float hf[8];
  #pragma unroll
  for(int e=0;e<8;++e) hf[e]=(float)hv[e]+(float)lv[e];
  float y[4];
  #pragma unroll
  for(int jj=0;jj<4;++jj){
    const float* wp=Wy+jj*HD+lane*8;
    float s=0.f;
    #pragma unroll
    for(int e=0;e<8;++e) s+=hf[e]*wp[e];
    #pragma unroll
    for(int off=32;off>=1;off>>=1) s+=__shfl_xor(s,off,64);
    y[jj]=s;
  }
  if(lane==0){
    float mu=0.25f*(y[0]+y[1]+y[2]+y[3]);
    float var=0.f;
    #pragma unroll
    for(int jj=0;jj<4;++jj){ float d=y[jj]-mu; var+=d*d; }
    var*=0.25f;
    float rs=rsqrtf(var+1e-6f);
    float z[4], zmax=-1e30f;
    #pragma unroll
    for(int jj=0;jj<4;++jj){ z[jj]=(y[jj]-mu)*rs*gamma[jj]+beta[jj]; zmax=fmaxf(zmax,z[jj]); }
    float es=0.f;
    #pragma unroll
    for(int jj=0;jj<4;++jj){ z[jj]=__expf(z[jj]-zmax); es+=z[jj]; }
    float inv=1.f/es;
    #pragma unroll
    for(int jj=0;jj<4;++jj) out0[(size_t)node*4+jj]=z[jj]*inv;
  }
}

// ---------------- root head ----------------
__global__ __launch_bounds__(256)
void k_root(const bf16* __restrict__ hhi, const bf16* __restrict__ hlo,
            const float* __restrict__ Wff, float* __restrict__ out1)
{
  const int gtid=blockIdx.x*256+threadIdx.x;
  const int tt=gtid>>6, lane=gtid&63;
  if(tt>=64) return;
  const size_t base=((size_t)tt*NPT+1364)*HD+lane*8;
  bf16x8 hv=*(const bf16x8*)(hhi+base);
  bf16x8 lv=*(const bf16x8*)(hlo+base);
  float hf[8];
  #pragma unroll
  for(int e=0;e<8;++e) hf[e]=(float)hv[e]+(float)lv[e];
  float y[4];
  #pragma unroll
  for(int jj=0;jj<4;++jj){
    const float* wp=Wff+jj*HD+lane*8;
    float s=0.f;
    #pragma unroll
    for(int e=0;e<8;++e) s+=hf[e]*wp[e];
    #pragma unroll
    for(int off=32;off>=1;off>>=1) s+=__shfl_xor(s,off,64);
    y[jj]=s;
  }
  if(lane==0){
    float zmax=fmaxf(fmaxf(y[0],y[1]),fmaxf(y[2],y[3]));
    float es=0.f, z[4];
    #pragma unroll
    for(int jj=0;jj<4;++jj){ z[jj]=__expf(y[jj]-zmax); es+=z[jj]; }
    float inv=1.f/es;
    #pragma unroll
    for(int jj=0;jj<4;++jj) out1[(size_t)tt*4+jj]=z[jj]*inv;
  }
}

extern "C" void kernel_launch(void* const* d_in, const int* in_sizes, int n_in,
                              void* d_out, int out_size, void* d_ws, size_t ws_size,
                              hipStream_t stream)
{
  const float* features=(const float*)d_in[0];
  const float* W_iou=(const float*)d_in[6];
  const float* b_iou=(const float*)d_in[7];
  const float* U_iou=(const float*)d_in[8];
  const float* W_f  =(const float*)d_in[9];
  const float* b_f  =(const float*)d_in[10];
  const float* U_f  =(const float*)d_in[11];
  const float* W_ff =(const float*)d_in[12];
  const float* W_sd =(const float*)d_in[13];
  const float* W_sd2=(const float*)d_in[14];
  const float* W_sf =(const float*)d_in[15];
  const float* ln_g =(const float*)d_in[16];
  const float* ln_b =(const float*)d_in[17];

  const int N=in_sizes[0]/768;   // 87360
  const int T=N/NPT;             // 64

  float* out0=(float*)d_out;
  float* out1=out0+(size_t)N*4;
  float* cbuf=out1+(size_t)T*4;  // c output region, used as live c-state

  char* p=(char*)d_ws;
  auto alloc=[&](size_t bytes){ char* r=p; p+=((bytes+255)&~(size_t)255); return r; };
  bf16*  f_hi =(bf16*) alloc((size_t)N*768*2);
  bf16*  f_lo =(bf16*) alloc((size_t)N*768*2);
  bf16*  hs_hi=(bf16*) alloc((size_t)16384*HD*2);
  bf16*  hs_lo=(bf16*) alloc((size_t)16384*HD*2);
  float* csum =(float*)alloc((size_t)16384*HD*4);
  bf16*  h_hi =(bf16*) alloc((size_t)N*HD*2);
  bf16*  h_lo =(bf16*) alloc((size_t)N*HD*2);
  bf16*  WcatI2=(bf16*)alloc((size_t)1536*2560*2);
  bf16*  WcatF2=(bf16*)alloc((size_t)512*2560*2);
  bf16*  WcatI =(bf16*)alloc((size_t)1536*3840*2);   // old layout, level-5 64-tile only
  float* Wcomb=(float*)alloc((size_t)512*512*4);
  float* Wy   =(float*)alloc((size_t)4*512*4);

  // conversions / weight prep
  { size_t n=(size_t)N*768;     k_split<<<(int)((n+255)/256),256,0,stream>>>(features,f_hi,f_lo,n); }
  { size_t n=(size_t)1536*2560; k_concat2560<<<(int)((n+255)/256),256,0,stream>>>(W_iou,U_iou,WcatI2,1536); }
  { size_t n=(size_t)512*2560;  k_concat2560<<<(int)((n+255)/256),256,0,stream>>>(W_f,U_f,WcatF2,512); }
  { size_t n=(size_t)1536*3840; k_concatHL<<<(int)((n+255)/256),256,0,stream>>>(W_iou,U_iou,WcatI,1536); }
  { dim3 g(8,8); k_wcomb<<<g,256,0,stream>>>(W_sd2,W_sd,Wcomb); }
  { k_wy<<<8,256,0,stream>>>(W_sf,Wcomb,Wy); }

  static const int starts[6]={0,1024,1280,1344,1360,1364};
  static const int csh[6]  ={10,8,6,4,2,0};
  static const int counts[6]={1024,256,64,16,4,1};

  // level 0 (leaves): regions fH(dual)+fL, K_A=1536
  { dim3 g((T*1024)/128, 8);
    k_iou128<<<g,256,0,stream>>>(f_hi,f_lo,hs_hi,hs_lo,WcatI2,b_iou,csum,h_hi,h_lo,cbuf,0,10,0); }

  for(int n=1;n<6;++n){
    int P=T*counts[n], E=T*counts[n-1];
    { int th=P*64; k_hsum<<<(th+255)/256,256,0,stream>>>(h_hi,h_lo,hs_hi,hs_lo,starts[n-1],csh[n-1],P); }
    { dim3 g(E/128,4);
      k_f128<<<g,256,0,stream>>>(f_hi,f_lo,h_hi,h_lo,WcatF2,b_f,cbuf,csum,starts[n],starts[n-1],csh[n-1]); }
    if(P>=128){
      dim3 g(P/128,8);
      k_iou128<<<g,256,0,stream>>>(f_hi,f_lo,hs_hi,hs_lo,WcatI2,b_iou,csum,h_hi,h_lo,cbuf,starts[n],csh[n],1);
    }else{
      dim3 g(P/64,8);
      k_iou<<<g,256,0,stream>>>(f_hi,f_lo,hs_hi,hs_lo,WcatI,b_iou,csum,h_hi,h_lo,cbuf,starts[n],csh[n],3840,3840,1);
    }
  }

  // heads (stance pass algebraically folded into Wy)
  { int th=N*64; k_final2<<<(th+255)/256,256,0,stream>>>(h_hi,h_lo,Wy,ln_g,ln_b,out0,N); }
  { k_root<<<16,256,0,stream>>>(h_hi,h_lo,W_ff,out1); }
}

// Round 7
// 2167.665 us; speedup vs baseline: 1.5892x; 1.0992x over previous
//
#include <hip/hip_runtime.h>
#include <hip/hip_bf16.h>
#include <math.h>

typedef __bf16 bf16;
typedef bf16 bf16x8 __attribute__((ext_vector_type(8)));
typedef float f32x4 __attribute__((ext_vector_type(4)));

#define NPT 1365
#define HD 512
#define NINT 341   // internal nodes per tree (256+64+16+4+1)

__device__ __forceinline__ float sigm(float x){ return 1.0f/(1.0f+__expf(-x)); }

__device__ __forceinline__ void gll16(const void* g, void* l){
  __builtin_amdgcn_global_load_lds((const __attribute__((address_space(1))) void*)g,
                                   (__attribute__((address_space(3))) void*)l, 16, 0, 0);
}

// ---------------- split fp32 -> bf16 hi/lo ----------------
__global__ void k_split(const float* __restrict__ s, bf16* __restrict__ hi,
                        bf16* __restrict__ lo, size_t n){
  size_t i=(size_t)blockIdx.x*blockDim.x+threadIdx.x;
  if(i<n){ float v=s[i]; bf16 h=(bf16)v; hi[i]=h; lo[i]=(bf16)(v-(float)h); }
}

// ---------------- generic [hi|lo] row concat: d[r][0..Ksrc)=hi, [Ksrc..2Ksrc)=lo ----------------
__global__ void k_catHL(const float* __restrict__ S, bf16* __restrict__ d,
                        int rows, int Ksrc){
  size_t i=(size_t)blockIdx.x*blockDim.x+threadIdx.x;
  int K=2*Ksrc;
  size_t tot=(size_t)rows*K;
  if(i>=tot) return;
  int r=(int)(i/K); int k=(int)(i-(size_t)r*K);
  float v=S[(size_t)r*Ksrc + (k<Ksrc?k:k-Ksrc)];
  bf16 h=(bf16)v;
  d[i]=(k<Ksrc)? h : (bf16)(v-(float)h);
}

// ---------------- weight concat K=2560: [Whi(768)|Uhi(512)|Wlo(768)|Ulo(512)] ----------------
__global__ void k_concat2560(const float* __restrict__ W, const float* __restrict__ U,
                             bf16* __restrict__ d, int rows){
  size_t i=(size_t)blockIdx.x*blockDim.x+threadIdx.x;
  const int K=2560;
  size_t tot=(size_t)rows*K;
  if(i>=tot) return;
  int r=(int)(i/K); int k=(int)(i-(size_t)r*K);
  float v; int lo=0;
  if(k<768)        v=W[(size_t)r*768+k];
  else if(k<1280)  v=U[(size_t)r*512+(k-768)];
  else if(k<2048){ v=W[(size_t)r*768+(k-1280)]; lo=1; }
  else           { v=U[(size_t)r*512+(k-2048)]; lo=1; }
  bf16 h=(bf16)v;
  d[i]= lo ? (bf16)(v-(float)h) : h;
}

// ---------------- old-layout concat K=3840 (level-5 64-tile iou only) ----------------
__global__ void k_concatHL3840(const float* __restrict__ W, const float* __restrict__ U,
                               bf16* __restrict__ d, int rows){
  size_t i=(size_t)blockIdx.x*blockDim.x+threadIdx.x;
  const int K=3840;
  size_t tot=(size_t)rows*K;
  if(i>=tot) return;
  int r=(int)(i/K); int k=(int)(i-(size_t)r*K);
  float v; int lo=0;
  if(k<768)        v=W[(size_t)r*768+k];
  else if(k<1536)  v=W[(size_t)r*768+(k-768)];
  else if(k<2048)  v=U[(size_t)r*512+(k-1536)];
  else if(k<2560)  v=U[(size_t)r*512+(k-2048)];
  else if(k<3328){ v=W[(size_t)r*768+(k-2560)]; lo=1; }
  else           { v=U[(size_t)r*512+(k-3328)]; lo=1; }
  bf16 h=(bf16)v;
  d[i]= lo ? (bf16)(v-(float)h) : h;
}

// ---------------- Wcomb = W_sd2 @ W_sd  (512x512, fp32 exact) ----------------
__global__ __launch_bounds__(256)
void k_wcomb(const float* __restrict__ W2, const float* __restrict__ W1,
             float* __restrict__ out){
  __shared__ float As[64][33];
  __shared__ float Bs[32][65];
  const int tid=threadIdx.x;
  const int i0=blockIdx.x*64, j0=blockIdx.y*64;
  const int tr=(tid>>4)*4, tc=(tid&15)*4;
  float acc[4][4];
  #pragma unroll
  for(int x=0;x<4;++x)
    #pragma unroll
    for(int y=0;y<4;++y) acc[x][y]=0.f;
  for(int k0=0;k0<1024;k0+=32){
    for(int l=tid;l<64*32;l+=256){ int r=l>>5,c=l&31; As[r][c]=W2[(size_t)(i0+r)*1024+k0+c]; }
    for(int l=tid;l<32*64;l+=256){ int r=l>>6,c=l&63; Bs[r][c]=W1[(size_t)(k0+r)*512+j0+c]; }
    __syncthreads();
    #pragma unroll 8
    for(int k=0;k<32;++k){
      float a[4],b[4];
      #pragma unroll
      for(int x=0;x<4;++x){ a[x]=As[tr+x][k]; b[x]=Bs[k][tc+x]; }
      #pragma unroll
      for(int x=0;x<4;++x)
        #pragma unroll
        for(int y=0;y<4;++y) acc[x][y]+=a[x]*b[y];
    }
    __syncthreads();
  }
  #pragma unroll
  for(int x=0;x<4;++x)
    #pragma unroll
    for(int y=0;y<4;++y) out[(size_t)(i0+tr+x)*512+j0+tc+y]=acc[x][y];
}

// ---------------- Wy[j,c] = Wsf[j,c] + sum_d Wsf[j,d]*Wcomb[d,c]  (4x512) ----------------
__global__ void k_wy(const float* __restrict__ Wsf, const float* __restrict__ Wcomb,
                     float* __restrict__ Wy){
  int idx=blockIdx.x*256+threadIdx.x;
  if(idx>=2048) return;
  int j=idx>>9, c=idx&511;
  float s=Wsf[j*512+c];
  for(int d=0;d<512;++d) s+=Wsf[j*512+d]*Wcomb[(size_t)d*512+c];
  Wy[(size_t)j*512+c]=s;
}

// ---------------- h_sum: fp32 sum of 4 children (hi+lo), split hi/lo ----------------
__global__ __launch_bounds__(256)
void k_hsum(const bf16* __restrict__ hhi, const bf16* __restrict__ hlo,
            bf16* __restrict__ hs_hi, bf16* __restrict__ hs_lo,
            int start_ch, int lcm1, int P){
  int idx=blockIdx.x*256+threadIdx.x;
  int m=idx>>6;
  if(m>=P) return;
  int c8=(idx&63)*8;
  int cm=m<<2;
  int t=cm>>lcm1, ci=cm-(t<<lcm1);
  const size_t base=((size_t)t*NPT+start_ch+ci)*HD+c8;
  float s[8];
  #pragma unroll
  for(int e=0;e<8;++e) s[e]=0.f;
  #pragma unroll
  for(int ch=0;ch<4;++ch){
    bf16x8 a=*(const bf16x8*)(hhi+base+(size_t)ch*HD);
    bf16x8 b=*(const bf16x8*)(hlo+base+(size_t)ch*HD);
    #pragma unroll
    for(int e=0;e<8;++e) s[e]+=(float)a[e]+(float)b[e];
  }
  bf16x8 oh,ol;
  #pragma unroll
  for(int e=0;e<8;++e){ bf16 hv=(bf16)s[e]; oh[e]=hv; ol[e]=(bf16)(s[e]-(float)hv); }
  *(bf16x8*)(hs_hi+(size_t)m*HD+c8)=oh;
  *(bf16x8*)(hs_lo+(size_t)m*HD+c8)=ol;
}

// ================= iou GEMM, 128 rows x 64 cols x 3 gates, K-dedup regions =================
__global__ __launch_bounds__(256,2)
void k_iou128(const bf16* __restrict__ fH, const bf16* __restrict__ fL,
              const bf16* __restrict__ hsH, const bf16* __restrict__ hsL,
              const bf16* __restrict__ Wcat, const float* __restrict__ bias,
              const float* __restrict__ csum, bf16* __restrict__ hbuf,
              bf16* __restrict__ hlo, float* __restrict__ cbuf,
              int start_n, int shift, int internal)
{
  __shared__ bf16 As[128][32];
  __shared__ bf16 Bs[6][64][32];
  const int tid=threadIdx.x;
  const int w=tid>>6, lane=tid&63;
  const int m0=blockIdx.x*128, n0=blockIdx.y*64;

  size_t frowA[2], hrowA[2];
  #pragma unroll
  for(int i=0;i<2;++i){
    int r=w*16+i*64+(lane>>2);
    int m=m0+r;
    int t=m>>shift, j=m-(t<<shift);
    frowA[i]=((size_t)t*NPT+start_n+j)*768;
    hrowA[i]=(size_t)m*HD;
  }
  const bf16* bPtr[6];
  #pragma unroll
  for(int i=0;i<6;++i){
    int row=(i>>1)*512 + n0 + w*16 + (lane>>2);
    bPtr[i]=Wcat+(size_t)row*2560;
  }
  const int acol=(lane&3)*8;

  f32x4 acc[3][4][2];
  #pragma unroll
  for(int g=0;g<3;++g)
    #pragma unroll
    for(int mi=0;mi<4;++mi)
      #pragma unroll
      for(int ni=0;ni<2;++ni) acc[g][mi][ni]=(f32x4){0.f,0.f,0.f,0.f};

  const int wr=(w>>1)*64, wc=(w&1)*32;
  const int lr=lane&15, lg=lane>>4;

  auto STEP=[&](const bf16* a0, const bf16* a1, int offH, int offL, bool dual){
    gll16(a0,&As[w*16][0]);
    gll16(a1,&As[w*16+64][0]);
    if(dual){
      #pragma unroll
      for(int i=0;i<6;++i)
        gll16(bPtr[i]+((i&1)?offL:offH)+acol,&Bs[i][w*16][0]);
    }else{
      #pragma unroll
      for(int i=0;i<3;++i)
        gll16(bPtr[2*i]+offH+acol,&Bs[2*i][w*16][0]);
    }
    __syncthreads();
    bf16x8 av[4];
    #pragma unroll
    for(int mi=0;mi<4;++mi) av[mi]=*(bf16x8*)&As[wr+mi*16+lr][lg*8];
    #pragma unroll
    for(int g=0;g<3;++g){
      #pragma unroll
      for(int ni=0;ni<2;++ni){
        bf16x8 bvh=*(bf16x8*)&Bs[2*g][wc+ni*16+lr][lg*8];
        #pragma unroll
        for(int mi=0;mi<4;++mi)
          acc[g][mi][ni]=__builtin_amdgcn_mfma_f32_16x16x32_bf16(av[mi],bvh,acc[g][mi][ni],0,0,0);
        if(dual){
          bf16x8 bvl=*(bf16x8*)&Bs[2*g+1][wc+ni*16+lr][lg*8];
          #pragma unroll
          for(int mi=0;mi<4;++mi)
            acc[g][mi][ni]=__builtin_amdgcn_mfma_f32_16x16x32_bf16(av[mi],bvl,acc[g][mi][ni],0,0,0);
        }
      }
    }
    __syncthreads();
  };

  for(int s=0;s<24;++s){ int kk=s<<5;
    STEP(fH+frowA[0]+kk+acol, fH+frowA[1]+kk+acol, kk, 1280+kk, true); }
  for(int s=0;s<24;++s){ int kk=s<<5;
    STEP(fL+frowA[0]+kk+acol, fL+frowA[1]+kk+acol, kk, 0, false); }
  if(internal){
    for(int s=0;s<16;++s){ int kk=s<<5;
      STEP(hsH+hrowA[0]+kk+acol, hsH+hrowA[1]+kk+acol, 768+kk, 2048+kk, true); }
    for(int s=0;s<16;++s){ int kk=s<<5;
      STEP(hsL+hrowA[0]+kk+acol, hsL+hrowA[1]+kk+acol, 768+kk, 0, false); }
  }

  #pragma unroll
  for(int mi=0;mi<4;++mi){
    #pragma unroll
    for(int ni=0;ni<2;++ni){
      const int col=n0+wc+ni*16+lr;
      const float bi=bias[col], bo=bias[col+512], bu=bias[col+1024];
      #pragma unroll
      for(int r=0;r<4;++r){
        const int mm=m0+wr+mi*16+lg*4+r;
        float iv=acc[0][mi][ni][r]+bi;
        float ov=acc[1][mi][ni][r]+bo;
        float uv=acc[2][mi][ni][r]+bu;
        float cn=sigm(iv)*tanhf(uv);
        if(internal) cn+=csum[(size_t)mm*HD+col];
        float hn=sigm(ov)*tanhf(cn);
        const int tt=mm>>shift, jj=mm-(tt<<shift);
        const size_t nd=((size_t)tt*NPT+start_n+jj)*HD+col;
        cbuf[nd]=cn;
        bf16 hh=(bf16)hn;
        hbuf[nd]=hh;
        hlo[nd]=(bf16)(hn-(float)hh);
      }
    }
  }
}

// ---------------- old 64-tile iou (level 5 only, P=64; K=3840 layout) ----------------
__global__ __launch_bounds__(256)
void k_iou(const bf16* __restrict__ fH, const bf16* __restrict__ fL,
           const bf16* __restrict__ hsH, const bf16* __restrict__ hsL,
           const bf16* __restrict__ Wcat, const float* __restrict__ bias,
           const float* __restrict__ csum, bf16* __restrict__ hbuf,
           bf16* __restrict__ hlo, float* __restrict__ cbuf,
           int start_n, int shift, int K, int KB, int internal)
{
  __shared__ bf16 As[64][40];
  __shared__ bf16 Bs[3][64][40];
  const int tid=threadIdx.x;
  const int m0=blockIdx.x*64, n0=blockIdx.y*64;
  const int srow=tid>>2, skc=(tid&3)*8;
  const int m=m0+srow;
  const int t=m>>shift, j=m-(t<<shift);
  const size_t frow=((size_t)t*NPT+start_n+j)*768;
  const bf16* aFH=fH+frow;
  const bf16* aFL=fL+frow;
  const bf16* aHH=hsH+(size_t)m*HD;
  const bf16* aHL=hsL+(size_t)m*HD;
  const bf16* bp0=Wcat+(size_t)(n0+srow)*KB;
  const bf16* bp1=Wcat+(size_t)(512+n0+srow)*KB;
  const bf16* bp2=Wcat+(size_t)(1024+n0+srow)*KB;

  f32x4 acc[3][2][2];
  #pragma unroll
  for(int g=0;g<3;++g)
    #pragma unroll
    for(int mi=0;mi<2;++mi)
      #pragma unroll
      for(int ni=0;ni<2;++ni) acc[g][mi][ni]=(f32x4){0.f,0.f,0.f,0.f};

  const int w=tid>>6, lane=tid&63;
  const int wr=(w>>1)*32, wc=(w&1)*32;
  const int lr=lane&15, lg=lane>>4;

  for(int k0=0;k0<K;k0+=32){
    const bf16* ap;
    if(internal){
      if(k0<768)        ap=aFH+k0;
      else if(k0<1536)  ap=aFL+(k0-768);
      else if(k0<2048)  ap=aHH+(k0-1536);
      else if(k0<2560)  ap=aHL+(k0-2048);
      else if(k0<3328)  ap=aFH+(k0-2560);
      else              ap=aHH+(k0-3328);
    }else{
      ap=(k0<768)? (aFH+k0) : ((k0<1536)? (aFL+(k0-768)) : (aFH+(k0-1536)));
    }
    *(bf16x8*)&As[srow][skc]=*(const bf16x8*)(ap+skc);
    *(bf16x8*)&Bs[0][srow][skc]=*(const bf16x8*)(bp0+k0+skc);
    *(bf16x8*)&Bs[1][srow][skc]=*(const bf16x8*)(bp1+k0+skc);
    *(bf16x8*)&Bs[2][srow][skc]=*(const bf16x8*)(bp2+k0+skc);
    __syncthreads();
    bf16x8 a0=*(bf16x8*)&As[wr+lr][lg*8];
    bf16x8 a1=*(bf16x8*)&As[wr+16+lr][lg*8];
    #pragma unroll
    for(int g=0;g<3;++g){
      #pragma unroll
      for(int ni=0;ni<2;++ni){
        bf16x8 bv=*(bf16x8*)&Bs[g][wc+ni*16+lr][lg*8];
        acc[g][0][ni]=__builtin_amdgcn_mfma_f32_16x16x32_bf16(a0,bv,acc[g][0][ni],0,0,0);
        acc[g][1][ni]=__builtin_amdgcn_mfma_f32_16x16x32_bf16(a1,bv,acc[g][1][ni],0,0,0);
      }
    }
    __syncthreads();
  }

  #pragma unroll
  for(int mi=0;mi<2;++mi){
    #pragma unroll
    for(int ni=0;ni<2;++ni){
      const int col=n0+wc+ni*16+lr;
      const float bi=bias[col], bo=bias[col+512], bu=bias[col+1024];
      #pragma unroll
      for(int r=0;r<4;++r){
        const int mm=m0+wr+mi*16+lg*4+r;
        float iv=acc[0][mi][ni][r]+bi;
        float ov=acc[1][mi][ni][r]+bo;
        float uv=acc[2][mi][ni][r]+bu;
        float cn=sigm(iv)*tanhf(uv);
        if(internal) cn+=csum[(size_t)mm*HD+col];
        float hn=sigm(ov)*tanhf(cn);
        const int tt=mm>>shift, jj=mm-(tt<<shift);
        const size_t nd=((size_t)tt*NPT+start_n+jj)*HD+col;
        cbuf[nd]=cn;
        bf16 hh=(bf16)hn;
        hbuf[nd]=hh;
        hlo[nd]=(bf16)(hn-(float)hh);
      }
    }
  }
}

// ================= XWf = x_internal @ W_f^T (split precision, fp32 out) =================
// M = 21824 internal nodes (t*341 + (j-1024)), N = 512
__global__ __launch_bounds__(256,2)
void k_xwf(const bf16* __restrict__ fH, const bf16* __restrict__ fL,
           const bf16* __restrict__ Wfc, float* __restrict__ XWf, int Mtot)
{
  __shared__ bf16 As[128][32];
  __shared__ bf16 BsH[128][32];
  __shared__ bf16 BsL[128][32];
  const int tid=threadIdx.x;
  const int w=tid>>6, lane=tid&63;
  const int m0=blockIdx.x*128, n0=blockIdx.y*128;

  size_t frowA[2];
  #pragma unroll
  for(int i=0;i<2;++i){
    int r=w*16+i*64+(lane>>2);
    int m=m0+r; if(m>=Mtot) m=Mtot-1;
    int t=m/NINT; int j=1024+(m-t*NINT);
    frowA[i]=((size_t)t*NPT+j)*768;
  }
  const bf16* bPtr[2];
  #pragma unroll
  for(int i=0;i<2;++i){
    int row=n0+(w*2+i)*16+(lane>>2);
    bPtr[i]=Wfc+(size_t)row*1536;
  }
  const int acol=(lane&3)*8;

  f32x4 acc[4][4];
  #pragma unroll
  for(int mi=0;mi<4;++mi)
    #pragma unroll
    for(int ni=0;ni<4;++ni) acc[mi][ni]=(f32x4){0.f,0.f,0.f,0.f};

  const int wr=(w>>1)*64, wc=(w&1)*64;
  const int lr=lane&15, lg=lane>>4;

  auto STEP=[&](const bf16* a0, const bf16* a1, int offH, int offL, bool dual){
    gll16(a0,&As[w*16][0]);
    gll16(a1,&As[w*16+64][0]);
    #pragma unroll
    for(int i=0;i<2;++i) gll16(bPtr[i]+offH+acol,&BsH[(w*2+i)*16][0]);
    if(dual){
      #pragma unroll
      for(int i=0;i<2;++i) gll16(bPtr[i]+offL+acol,&BsL[(w*2+i)*16][0]);
    }
    __syncthreads();
    bf16x8 av[4];
    #pragma unroll
    for(int mi=0;mi<4;++mi) av[mi]=*(bf16x8*)&As[wr+mi*16+lr][lg*8];
    #pragma unroll
    for(int ni=0;ni<4;++ni){
      bf16x8 bvh=*(bf16x8*)&BsH[wc+ni*16+lr][lg*8];
      #pragma unroll
      for(int mi=0;mi<4;++mi)
        acc[mi][ni]=__builtin_amdgcn_mfma_f32_16x16x32_bf16(av[mi],bvh,acc[mi][ni],0,0,0);
      if(dual){
        bf16x8 bvl=*(bf16x8*)&BsL[wc+ni*16+lr][lg*8];
        #pragma unroll
        for(int mi=0;mi<4;++mi)
          acc[mi][ni]=__builtin_amdgcn_mfma_f32_16x16x32_bf16(av[mi],bvl,acc[mi][ni],0,0,0);
      }
    }
    __syncthreads();
  };

  for(int s=0;s<24;++s){ int kk=s<<5;
    STEP(fH+frowA[0]+kk+acol, fH+frowA[1]+kk+acol, kk, 768+kk, true); }
  for(int s=0;s<24;++s){ int kk=s<<5;
    STEP(fL+frowA[0]+kk+acol, fL+frowA[1]+kk+acol, kk, 0, false); }

  #pragma unroll
  for(int mi=0;mi<4;++mi){
    #pragma unroll
    for(int ni=0;ni<4;++ni){
      const int col=n0+wc+ni*16+lr;
      #pragma unroll
      for(int r=0;r<4;++r){
        const int mm=m0+wr+mi*16+lg*4+r;
        if(mm<Mtot) XWf[(size_t)mm*512+col]=acc[mi][ni][r];
      }
    }
  }
}

// ================= Uh-only forget-gate GEMM + fused epilogue =================
// A = h_child (hi dual, lo single), K-equiv 1536; epilogue adds XWf[parent]+b
__global__ __launch_bounds__(256,2)
void k_uh_f(const bf16* __restrict__ hhi, const bf16* __restrict__ hlo,
            const bf16* __restrict__ Ufc, const float* __restrict__ bias,
            const float* __restrict__ XWf, const float* __restrict__ cbuf,
            float* __restrict__ csum, int start_ch, int lc, int xwoff)
{
  __shared__ bf16 As[128][32];
  __shared__ bf16 BsH[128][32];
  __shared__ bf16 BsL[128][32];
  const int tid=threadIdx.x;
  const int w=tid>>6, lane=tid&63;
  const int e0=blockIdx.x*128, n0=blockIdx.y*128;

  size_t hrowA[2];
  #pragma unroll
  for(int i=0;i<2;++i){
    int r=w*16+i*64+(lane>>2);
    int e=e0+r;
    int t=e>>lc, ei=e-(t<<lc);
    hrowA[i]=((size_t)t*NPT+start_ch+ei)*HD;
  }
  const bf16* bPtr[2];
  #pragma unroll
  for(int i=0;i<2;++i){
    int row=n0+(w*2+i)*16+(lane>>2);
    bPtr[i]=Ufc+(size_t)row*1024;
  }
  const int acol=(lane&3)*8;

  f32x4 acc[4][4];
  #pragma unroll
  for(int mi=0;mi<4;++mi)
    #pragma unroll
    for(int ni=0;ni<4;++ni) acc[mi][ni]=(f32x4){0.f,0.f,0.f,0.f};

  const int wr=(w>>1)*64, wc=(w&1)*64;
  const int lr=lane&15, lg=lane>>4;

  auto STEP=[&](const bf16* a0, const bf16* a1, int offH, int offL, bool dual){
    gll16(a0,&As[w*16][0]);
    gll16(a1,&As[w*16+64][0]);
    #pragma unroll
    for(int i=0;i<2;++i) gll16(bPtr[i]+offH+acol,&BsH[(w*2+i)*16][0]);
    if(dual){
      #pragma unroll
      for(int i=0;i<2;++i) gll16(bPtr[i]+offL+acol,&BsL[(w*2+i)*16][0]);
    }
    __syncthreads();
    bf16x8 av[4];
    #pragma unroll
    for(int mi=0;mi<4;++mi) av[mi]=*(bf16x8*)&As[wr+mi*16+lr][lg*8];
    #pragma unroll
    for(int ni=0;ni<4;++ni){
      bf16x8 bvh=*(bf16x8*)&BsH[wc+ni*16+lr][lg*8];
      #pragma unroll
      for(int mi=0;mi<4;++mi)
        acc[mi][ni]=__builtin_amdgcn_mfma_f32_16x16x32_bf16(av[mi],bvh,acc[mi][ni],0,0,0);
      if(dual){
        bf16x8 bvl=*(bf16x8*)&BsL[wc+ni*16+lr][lg*8];
        #pragma unroll
        for(int mi=0;mi<4;++mi)
          acc[mi][ni]=__builtin_amdgcn_mfma_f32_16x16x32_bf16(av[mi],bvl,acc[mi][ni],0,0,0);
      }
    }
    __syncthreads();
  };

  for(int s=0;s<16;++s){ int kk=s<<5;
    STEP(hhi+hrowA[0]+kk+acol, hhi+hrowA[1]+kk+acol, kk, 512+kk, true); }
  for(int s=0;s<16;++s){ int kk=s<<5;
    STEP(hlo+hrowA[0]+kk+acol, hlo+hrowA[1]+kk+acol, kk, 0, false); }

  #pragma unroll
  for(int mi=0;mi<4;++mi){
    const int ebase=e0+wr+mi*16+lg*4;
    const int tt=ebase>>lc, eib=ebase-(tt<<lc);
    const int inode=tt*NINT + xwoff + (eib>>2);
    #pragma unroll
    for(int ni=0;ni<4;++ni){
      const int col=n0+wc+ni*16+lr;
      const float base=bias[col]+XWf[(size_t)inode*512+col];
      const size_t chbase=((size_t)tt*NPT+start_ch+eib)*HD+col;
      float s=0.f;
      #pragma unroll
      for(int r=0;r<4;++r){
        float fv=sigm(acc[mi][ni][r]+base);
        s+=fv*cbuf[chbase+(size_t)r*HD];
      }
      csum[((size_t)(ebase>>2))*HD+col]=s;
    }
  }
}

// ---------------- final head: y = (h_hi+h_lo) @ Wy^T, LayerNorm(4), softmax ----------------
__global__ __launch_bounds__(256)
void k_final2(const bf16* __restrict__ hhi, const bf16* __restrict__ hlo,
              const float* __restrict__ Wy, const float* __restrict__ gamma,
              const float* __restrict__ beta, float* __restrict__ out0, int Nn)
{
  const int gtid=blockIdx.x*256+threadIdx.x;
  const int node=gtid>>6, lane=gtid&63;
  if(node>=Nn) return;
  const size_t base=(size_t)node*HD+lane*8;
  bf16x8 hv=*(const bf16x8*)(hhi+base);
  bf16x8 lv=*(const bf16x8*)(hlo+base);
  float hf[8];
  #pragma unroll
  for(int e=0;e<8;++e) hf[e]=(float)hv[e]+(float)lv[e];
  float y[4];
  #pragma unroll
  for(int jj=0;jj<4;++jj){
    const float* wp=Wy+jj*HD+lane*8;
    float s=0.f;
    #pragma unroll
    for(int e=0;e<8;++e) s+=hf[e]*wp[e];
    #pragma unroll
    for(int off=32;off>=1;off>>=1) s+=__shfl_xor(s,off,64);
    y[jj]=s;
  }
  if(lane==0){
    float mu=0.25f*(y[0]+y[1]+y[2]+y[3]);
    float var=0.f;
    #pragma unroll
    for(int jj=0;jj<4;++jj){ float d=y[jj]-mu; var+=d*d; }
    var*=0.25f;
    float rs=rsqrtf(var+1e-6f);
    float z[4], zmax=-1e30f;
    #pragma unroll
    for(int jj=0;jj<4;++jj){ z[jj]=(y[jj]-mu)*rs*gamma[jj]+beta[jj]; zmax=fmaxf(zmax,z[jj]); }
    float es=0.f;
    #pragma unroll
    for(int jj=0;jj<4;++jj){ z[jj]=__expf(z[jj]-zmax); es+=z[jj]; }
    float inv=1.f/es;
    #pragma unroll
    for(int jj=0;jj<4;++jj) out0[(size_t)node*4+jj]=z[jj]*inv;
  }
}

// ---------------- root head ----------------
__global__ __launch_bounds__(256)
void k_root(const bf16* __restrict__ hhi, const bf16* __restrict__ hlo,
            const float* __restrict__ Wff, float* __restrict__ out1)
{
  const int gtid=blockIdx.x*256+threadIdx.x;
  const int tt=gtid>>6, lane=gtid&63;
  if(tt>=64) return;
  const size_t base=((size_t)tt*NPT+1364)*HD+lane*8;
  bf16x8 hv=*(const bf16x8*)(hhi+base);
  bf16x8 lv=*(const bf16x8*)(hlo+base);
  float hf[8];
  #pragma unroll
  for(int e=0;e<8;++e) hf[e]=(float)hv[e]+(float)lv[e];
  float y[4];
  #pragma unroll
  for(int jj=0;jj<4;++jj){
    const float* wp=Wff+jj*HD+lane*8;
    float s=0.f;
    #pragma unroll
    for(int e=0;e<8;++e) s+=hf[e]*wp[e];
    #pragma unroll
    for(int off=32;off>=1;off>>=1) s+=__shfl_xor(s,off,64);
    y[jj]=s;
  }
  if(lane==0){
    float zmax=fmaxf(fmaxf(y[0],y[1]),fmaxf(y[2],y[3]));
    float es=0.f, z[4];
    #pragma unroll
    for(int jj=0;jj<4;++jj){ z[jj]=__expf(y[jj]-zmax); es+=z[jj]; }
    float inv=1.f/es;
    #pragma unroll
    for(int jj=0;jj<4;++jj) out1[(size_t)tt*4+jj]=z[jj]*inv;
  }
}

extern "C" void kernel_launch(void* const* d_in, const int* in_sizes, int n_in,
                              void* d_out, int out_size, void* d_ws, size_t ws_size,
                              hipStream_t stream)
{
  const float* features=(const float*)d_in[0];
  const float* W_iou=(const float*)d_in[6];
  const float* b_iou=(const float*)d_in[7];
  const float* U_iou=(const float*)d_in[8];
  const float* W_f  =(const float*)d_in[9];
  const float* b_f  =(const float*)d_in[10];
  const float* U_f  =(const float*)d_in[11];
  const float* W_ff =(const float*)d_in[12];
  const float* W_sd =(const float*)d_in[13];
  const float* W_sd2=(const float*)d_in[14];
  const float* W_sf =(const float*)d_in[15];
  const float* ln_g =(const float*)d_in[16];
  const float* ln_b =(const float*)d_in[17];

  const int N=in_sizes[0]/768;   // 87360
  const int T=N/NPT;             // 64
  const int MINT=T*NINT;         // 21824 internal nodes

  float* out0=(float*)d_out;
  float* out1=out0+(size_t)N*4;
  float* cbuf=out1+(size_t)T*4;  // c output region, used as live c-state

  char* p=(char*)d_ws;
  auto alloc=[&](size_t bytes){ char* r=p; p+=((bytes+255)&~(size_t)255); return r; };
  bf16*  f_hi =(bf16*) alloc((size_t)N*768*2);
  bf16*  f_lo =(bf16*) alloc((size_t)N*768*2);
  bf16*  hs_hi=(bf16*) alloc((size_t)16384*HD*2);
  bf16*  hs_lo=(bf16*) alloc((size_t)16384*HD*2);
  float* csum =(float*)alloc((size_t)16384*HD*4);
  bf16*  h_hi =(bf16*) alloc((size_t)N*HD*2);
  bf16*  h_lo =(bf16*) alloc((size_t)N*HD*2);
  bf16*  WcatI2=(bf16*)alloc((size_t)1536*2560*2);
  bf16*  WcatI =(bf16*)alloc((size_t)1536*3840*2);   // level-5 64-tile layout
  bf16*  Wfc  =(bf16*) alloc((size_t)512*1536*2);
  bf16*  Ufc  =(bf16*) alloc((size_t)512*1024*2);
  float* Wcomb=(float*)alloc((size_t)512*512*4);
  float* Wy   =(float*)alloc((size_t)4*512*4);
  float* XWf  =(float*)alloc((size_t)MINT*512*4);    // 44.7 MB

  // conversions / weight prep
  { size_t n=(size_t)N*768;     k_split<<<(int)((n+255)/256),256,0,stream>>>(features,f_hi,f_lo,n); }
  { size_t n=(size_t)1536*2560; k_concat2560<<<(int)((n+255)/256),256,0,stream>>>(W_iou,U_iou,WcatI2,1536); }
  { size_t n=(size_t)1536*3840; k_concatHL3840<<<(int)((n+255)/256),256,0,stream>>>(W_iou,U_iou,WcatI,1536); }
  { size_t n=(size_t)512*1536;  k_catHL<<<(int)((n+255)/256),256,0,stream>>>(W_f,Wfc,512,768); }
  { size_t n=(size_t)512*1024;  k_catHL<<<(int)((n+255)/256),256,0,stream>>>(U_f,Ufc,512,512); }
  { dim3 g(8,8); k_wcomb<<<g,256,0,stream>>>(W_sd2,W_sd,Wcomb); }
  { k_wy<<<8,256,0,stream>>>(W_sf,Wcomb,Wy); }

  // upfront: XWf for all internal nodes (independent of recursion)
  { dim3 g((MINT+127)/128, 4);
    k_xwf<<<g,256,0,stream>>>(f_hi,f_lo,Wfc,XWf,MINT); }

  static const int starts[6]={0,1024,1280,1344,1360,1364};
  static const int csh[6]  ={10,8,6,4,2,0};
  static const int counts[6]={1024,256,64,16,4,1};
  static const int xwoffs[6]={0,0,256,320,336,340};

  // level 0 (leaves)
  { dim3 g((T*1024)/128, 8);
    k_iou128<<<g,256,0,stream>>>(f_hi,f_lo,hs_hi,hs_lo,WcatI2,b_iou,csum,h_hi,h_lo,cbuf,0,10,0); }

  for(int n=1;n<6;++n){
    int P=T*counts[n], E=T*counts[n-1];
    { int th=P*64; k_hsum<<<(th+255)/256,256,0,stream>>>(h_hi,h_lo,hs_hi,hs_lo,starts[n-1],csh[n-1],P); }
    { dim3 g(E/128,4);
      k_uh_f<<<g,256,0,stream>>>(h_hi,h_lo,Ufc,b_f,XWf,cbuf,csum,starts[n-1],csh[n-1],xwoffs[n]); }
    if(P>=128){
      dim3 g(P/128,8);
      k_iou128<<<g,256,0,stream>>>(f_hi,f_lo,hs_hi,hs_lo,WcatI2,b_iou,csum,h_hi,h_lo,cbuf,starts[n],csh[n],1);
    }else{
      dim3 g(P/64,8);
      k_iou<<<g,256,0,stream>>>(f_hi,f_lo,hs_hi,hs_lo,WcatI,b_iou,csum,h_hi,h_lo,cbuf,starts[n],csh[n],3840,3840,1);
    }
  }

  // heads (stance folded into Wy)
  { int th=N*64; k_final2<<<(th+255)/256,256,0,stream>>>(h_hi,h_lo,Wy,ln_g,ln_b,out0,N); }
  { k_root<<<16,256,0,stream>>>(h_hi,h_lo,W_ff,out1); }
}

// Round 8
// 2049.033 us; speedup vs baseline: 1.6813x; 1.0579x over previous
//
#include <hip/hip_runtime.h>
#include <hip/hip_bf16.h>
#include <math.h>

typedef __bf16 bf16;
typedef bf16 bf16x8 __attribute__((ext_vector_type(8)));
typedef float f32x4 __attribute__((ext_vector_type(4)));

#define NPT 1365
#define HD 512
#define NINT 341   // internal nodes per tree (256+64+16+4+1)

__device__ __forceinline__ float sigm(float x){ return 1.0f/(1.0f+__expf(-x)); }

__device__ __forceinline__ void gll16(const void* g, void* l){
  __builtin_amdgcn_global_load_lds((const __attribute__((address_space(1))) void*)g,
                                   (__attribute__((address_space(3))) void*)l, 16, 0, 0);
}

// ---------------- split fp32 -> bf16 hi/lo, 8 elems/thread ----------------
__global__ void k_split8(const float* __restrict__ s, bf16* __restrict__ hi,
                         bf16* __restrict__ lo, size_t n8){
  size_t i=(size_t)blockIdx.x*blockDim.x+threadIdx.x;
  if(i>=n8) return;
  const float4* sp=(const float4*)(s+i*8);
  float4 a=sp[0], b=sp[1];
  float v[8]={a.x,a.y,a.z,a.w,b.x,b.y,b.z,b.w};
  bf16x8 h,l;
  #pragma unroll
  for(int e=0;e<8;++e){ bf16 hh=(bf16)v[e]; h[e]=hh; l[e]=(bf16)(v[e]-(float)hh); }
  *(bf16x8*)(hi+i*8)=h;
  *(bf16x8*)(lo+i*8)=l;
}

// ---------------- generic [hi|lo] row concat ----------------
__global__ void k_catHL(const float* __restrict__ S, bf16* __restrict__ d,
                        int rows, int Ksrc){
  size_t i=(size_t)blockIdx.x*blockDim.x+threadIdx.x;
  int K=2*Ksrc;
  size_t tot=(size_t)rows*K;
  if(i>=tot) return;
  int r=(int)(i/K); int k=(int)(i-(size_t)r*K);
  float v=S[(size_t)r*Ksrc + (k<Ksrc?k:k-Ksrc)];
  bf16 h=(bf16)v;
  d[i]=(k<Ksrc)? h : (bf16)(v-(float)h);
}

// ---------------- weight concat K=2560: [Whi(768)|Uhi(512)|Wlo(768)|Ulo(512)] ----------------
__global__ void k_concat2560(const float* __restrict__ W, const float* __restrict__ U,
                             bf16* __restrict__ d, int rows){
  size_t i=(size_t)blockIdx.x*blockDim.x+threadIdx.x;
  const int K=2560;
  size_t tot=(size_t)rows*K;
  if(i>=tot) return;
  int r=(int)(i/K); int k=(int)(i-(size_t)r*K);
  float v; int lo=0;
  if(k<768)        v=W[(size_t)r*768+k];
  else if(k<1280)  v=U[(size_t)r*512+(k-768)];
  else if(k<2048){ v=W[(size_t)r*768+(k-1280)]; lo=1; }
  else           { v=U[(size_t)r*512+(k-2048)]; lo=1; }
  bf16 h=(bf16)v;
  d[i]= lo ? (bf16)(v-(float)h) : h;
}

// ---------------- old-layout concat K=3840 (level-5 64-tile iou only) ----------------
__global__ void k_concatHL3840(const float* __restrict__ W, const float* __restrict__ U,
                               bf16* __restrict__ d, int rows){
  size_t i=(size_t)blockIdx.x*blockDim.x+threadIdx.x;
  const int K=3840;
  size_t tot=(size_t)rows*K;
  if(i>=tot) return;
  int r=(int)(i/K); int k=(int)(i-(size_t)r*K);
  float v; int lo=0;
  if(k<768)        v=W[(size_t)r*768+k];
  else if(k<1536)  v=W[(size_t)r*768+(k-768)];
  else if(k<2048)  v=U[(size_t)r*512+(k-1536)];
  else if(k<2560)  v=U[(size_t)r*512+(k-2048)];
  else if(k<3328){ v=W[(size_t)r*768+(k-2560)]; lo=1; }
  else           { v=U[(size_t)r*512+(k-3328)]; lo=1; }
  bf16 h=(bf16)v;
  d[i]= lo ? (bf16)(v-(float)h) : h;
}

// ---------------- Wcomb = W_sd2 @ W_sd  (512x512, fp32 exact) ----------------
__global__ __launch_bounds__(256)
void k_wcomb(const float* __restrict__ W2, const float* __restrict__ W1,
             float* __restrict__ out){
  __shared__ float As[64][33];
  __shared__ float Bs[32][65];
  const int tid=threadIdx.x;
  const int i0=blockIdx.x*64, j0=blockIdx.y*64;
  const int tr=(tid>>4)*4, tc=(tid&15)*4;
  float acc[4][4];
  #pragma unroll
  for(int x=0;x<4;++x)
    #pragma unroll
    for(int y=0;y<4;++y) acc[x][y]=0.f;
  for(int k0=0;k0<1024;k0+=32){
    for(int l=tid;l<64*32;l+=256){ int r=l>>5,c=l&31; As[r][c]=W2[(size_t)(i0+r)*1024+k0+c]; }
    for(int l=tid;l<32*64;l+=256){ int r=l>>6,c=l&63; Bs[r][c]=W1[(size_t)(k0+r)*512+j0+c]; }
    __syncthreads();
    #pragma unroll 8
    for(int k=0;k<32;++k){
      float a[4],b[4];
      #pragma unroll
      for(int x=0;x<4;++x){ a[x]=As[tr+x][k]; b[x]=Bs[k][tc+x]; }
      #pragma unroll
      for(int x=0;x<4;++x)
        #pragma unroll
        for(int y=0;y<4;++y) acc[x][y]+=a[x]*b[y];
    }
    __syncthreads();
  }
  #pragma unroll
  for(int x=0;x<4;++x)
    #pragma unroll
    for(int y=0;y<4;++y) out[(size_t)(i0+tr+x)*512+j0+tc+y]=acc[x][y];
}

// ---------------- Wy[j,c] = Wsf[j,c] + sum_d Wsf[j,d]*Wcomb[d,c]  (4x512) ----------------
__global__ void k_wy(const float* __restrict__ Wsf, const float* __restrict__ Wcomb,
                     float* __restrict__ Wy){
  int idx=blockIdx.x*256+threadIdx.x;
  if(idx>=2048) return;
  int j=idx>>9, c=idx&511;
  float s=Wsf[j*512+c];
  for(int d=0;d<512;++d) s+=Wsf[j*512+d]*Wcomb[(size_t)d*512+c];
  Wy[(size_t)j*512+c]=s;
}

// ================= iou GEMM, 128 rows x 64 cols x 3 gates, K-dedup regions =================
// grid: (8, M/128)  -> n0 = x*64, m0 = y*128  (A read once into L3, B pinned per XCD)
__global__ __launch_bounds__(256,2)
void k_iou128(const bf16* __restrict__ fH, const bf16* __restrict__ fL,
              const bf16* __restrict__ hsH, const bf16* __restrict__ hsL,
              const bf16* __restrict__ Wcat, const float* __restrict__ bias,
              const float* __restrict__ csum, bf16* __restrict__ hbuf,
              bf16* __restrict__ hlo, float* __restrict__ cbuf,
              int start_n, int shift, int internal)
{
  __shared__ bf16 As[128][32];
  __shared__ bf16 Bs[6][64][32];
  const int tid=threadIdx.x;
  const int w=tid>>6, lane=tid&63;
  const int m0=blockIdx.y*128, n0=blockIdx.x*64;

  size_t frowA[2], hrowA[2];
  #pragma unroll
  for(int i=0;i<2;++i){
    int r=w*16+i*64+(lane>>2);
    int m=m0+r;
    int t=m>>shift, j=m-(t<<shift);
    frowA[i]=((size_t)t*NPT+start_n+j)*768;
    hrowA[i]=(size_t)m*HD;
  }
  const bf16* bPtr[6];
  #pragma unroll
  for(int i=0;i<6;++i){
    int row=(i>>1)*512 + n0 + w*16 + (lane>>2);
    bPtr[i]=Wcat+(size_t)row*2560;
  }
  const int acol=(lane&3)*8;

  f32x4 acc[3][4][2];
  #pragma unroll
  for(int g=0;g<3;++g)
    #pragma unroll
    for(int mi=0;mi<4;++mi)
      #pragma unroll
      for(int ni=0;ni<2;++ni) acc[g][mi][ni]=(f32x4){0.f,0.f,0.f,0.f};

  const int wr=(w>>1)*64, wc=(w&1)*32;
  const int lr=lane&15, lg=lane>>4;

  auto STEP=[&](const bf16* a0, const bf16* a1, int offH, int offL, bool dual){
    gll16(a0,&As[w*16][0]);
    gll16(a1,&As[w*16+64][0]);
    if(dual){
      #pragma unroll
      for(int i=0;i<6;++i)
        gll16(bPtr[i]+((i&1)?offL:offH)+acol,&Bs[i][w*16][0]);
    }else{
      #pragma unroll
      for(int i=0;i<3;++i)
        gll16(bPtr[2*i]+offH+acol,&Bs[2*i][w*16][0]);
    }
    __syncthreads();
    bf16x8 av[4];
    #pragma unroll
    for(int mi=0;mi<4;++mi) av[mi]=*(bf16x8*)&As[wr+mi*16+lr][lg*8];
    #pragma unroll
    for(int g=0;g<3;++g){
      #pragma unroll
      for(int ni=0;ni<2;++ni){
        bf16x8 bvh=*(bf16x8*)&Bs[2*g][wc+ni*16+lr][lg*8];
        #pragma unroll
        for(int mi=0;mi<4;++mi)
          acc[g][mi][ni]=__builtin_amdgcn_mfma_f32_16x16x32_bf16(av[mi],bvh,acc[g][mi][ni],0,0,0);
        if(dual){
          bf16x8 bvl=*(bf16x8*)&Bs[2*g+1][wc+ni*16+lr][lg*8];
          #pragma unroll
          for(int mi=0;mi<4;++mi)
            acc[g][mi][ni]=__builtin_amdgcn_mfma_f32_16x16x32_bf16(av[mi],bvl,acc[g][mi][ni],0,0,0);
        }
      }
    }
    __syncthreads();
  };

  for(int s=0;s<24;++s){ int kk=s<<5;
    STEP(fH+frowA[0]+kk+acol, fH+frowA[1]+kk+acol, kk, 1280+kk, true); }
  for(int s=0;s<24;++s){ int kk=s<<5;
    STEP(fL+frowA[0]+kk+acol, fL+frowA[1]+kk+acol, kk, 0, false); }
  if(internal){
    for(int s=0;s<16;++s){ int kk=s<<5;
      STEP(hsH+hrowA[0]+kk+acol, hsH+hrowA[1]+kk+acol, 768+kk, 2048+kk, true); }
    for(int s=0;s<16;++s){ int kk=s<<5;
      STEP(hsL+hrowA[0]+kk+acol, hsL+hrowA[1]+kk+acol, 768+kk, 0, false); }
  }

  #pragma unroll
  for(int mi=0;mi<4;++mi){
    #pragma unroll
    for(int ni=0;ni<2;++ni){
      const int col=n0+wc+ni*16+lr;
      const float bi=bias[col], bo=bias[col+512], bu=bias[col+1024];
      #pragma unroll
      for(int r=0;r<4;++r){
        const int mm=m0+wr+mi*16+lg*4+r;
        float iv=acc[0][mi][ni][r]+bi;
        float ov=acc[1][mi][ni][r]+bo;
        float uv=acc[2][mi][ni][r]+bu;
        float cn=sigm(iv)*tanhf(uv);
        if(internal) cn+=csum[(size_t)mm*HD+col];
        float hn=sigm(ov)*tanhf(cn);
        const int tt=mm>>shift, jj=mm-(tt<<shift);
        const size_t nd=((size_t)tt*NPT+start_n+jj)*HD+col;
        cbuf[nd]=cn;
        bf16 hh=(bf16)hn;
        hbuf[nd]=hh;
        hlo[nd]=(bf16)(hn-(float)hh);
      }
    }
  }
}

// ---------------- old 64-tile iou (level 5 only, P=64; K=3840 layout) ----------------
__global__ __launch_bounds__(256)
void k_iou(const bf16* __restrict__ fH, const bf16* __restrict__ fL,
           const bf16* __restrict__ hsH, const bf16* __restrict__ hsL,
           const bf16* __restrict__ Wcat, const float* __restrict__ bias,
           const float* __restrict__ csum, bf16* __restrict__ hbuf,
           bf16* __restrict__ hlo, float* __restrict__ cbuf,
           int start_n, int shift, int K, int KB, int internal)
{
  __shared__ bf16 As[64][40];
  __shared__ bf16 Bs[3][64][40];
  const int tid=threadIdx.x;
  const int m0=blockIdx.x*64, n0=blockIdx.y*64;
  const int srow=tid>>2, skc=(tid&3)*8;
  const int m=m0+srow;
  const int t=m>>shift, j=m-(t<<shift);
  const size_t frow=((size_t)t*NPT+start_n+j)*768;
  const bf16* aFH=fH+frow;
  const bf16* aFL=fL+frow;
  const bf16* aHH=hsH+(size_t)m*HD;
  const bf16* aHL=hsL+(size_t)m*HD;
  const bf16* bp0=Wcat+(size_t)(n0+srow)*KB;
  const bf16* bp1=Wcat+(size_t)(512+n0+srow)*KB;
  const bf16* bp2=Wcat+(size_t)(1024+n0+srow)*KB;

  f32x4 acc[3][2][2];
  #pragma unroll
  for(int g=0;g<3;++g)
    #pragma unroll
    for(int mi=0;mi<2;++mi)
      #pragma unroll
      for(int ni=0;ni<2;++ni) acc[g][mi][ni]=(f32x4){0.f,0.f,0.f,0.f};

  const int w=tid>>6, lane=tid&63;
  const int wr=(w>>1)*32, wc=(w&1)*32;
  const int lr=lane&15, lg=lane>>4;

  for(int k0=0;k0<K;k0+=32){
    const bf16* ap;
    if(internal){
      if(k0<768)        ap=aFH+k0;
      else if(k0<1536)  ap=aFL+(k0-768);
      else if(k0<2048)  ap=aHH+(k0-1536);
      else if(k0<2560)  ap=aHL+(k0-2048);
      else if(k0<3328)  ap=aFH+(k0-2560);
      else              ap=aHH+(k0-3328);
    }else{
      ap=(k0<768)? (aFH+k0) : ((k0<1536)? (aFL+(k0-768)) : (aFH+(k0-1536)));
    }
    *(bf16x8*)&As[srow][skc]=*(const bf16x8*)(ap+skc);
    *(bf16x8*)&Bs[0][srow][skc]=*(const bf16x8*)(bp0+k0+skc);
    *(bf16x8*)&Bs[1][srow][skc]=*(const bf16x8*)(bp1+k0+skc);
    *(bf16x8*)&Bs[2][srow][skc]=*(const bf16x8*)(bp2+k0+skc);
    __syncthreads();
    bf16x8 a0=*(bf16x8*)&As[wr+lr][lg*8];
    bf16x8 a1=*(bf16x8*)&As[wr+16+lr][lg*8];
    #pragma unroll
    for(int g=0;g<3;++g){
      #pragma unroll
      for(int ni=0;ni<2;++ni){
        bf16x8 bv=*(bf16x8*)&Bs[g][wc+ni*16+lr][lg*8];
        acc[g][0][ni]=__builtin_amdgcn_mfma_f32_16x16x32_bf16(a0,bv,acc[g][0][ni],0,0,0);
        acc[g][1][ni]=__builtin_amdgcn_mfma_f32_16x16x32_bf16(a1,bv,acc[g][1][ni],0,0,0);
      }
    }
    __syncthreads();
  }

  #pragma unroll
  for(int mi=0;mi<2;++mi){
    #pragma unroll
    for(int ni=0;ni<2;++ni){
      const int col=n0+wc+ni*16+lr;
      const float bi=bias[col], bo=bias[col+512], bu=bias[col+1024];
      #pragma unroll
      for(int r=0;r<4;++r){
        const int mm=m0+wr+mi*16+lg*4+r;
        float iv=acc[0][mi][ni][r]+bi;
        float ov=acc[1][mi][ni][r]+bo;
        float uv=acc[2][mi][ni][r]+bu;
        float cn=sigm(iv)*tanhf(uv);
        if(internal) cn+=csum[(size_t)mm*HD+col];
        float hn=sigm(ov)*tanhf(cn);
        const int tt=mm>>shift, jj=mm-(tt<<shift);
        const size_t nd=((size_t)tt*NPT+start_n+jj)*HD+col;
        cbuf[nd]=cn;
        bf16 hh=(bf16)hn;
        hbuf[nd]=hh;
        hlo[nd]=(bf16)(hn-(float)hh);
      }
    }
  }
}

// ================= XWf = x_internal @ W_f^T (split precision, fp32 out) =================
// grid: (4, ceil(M/128))
__global__ __launch_bounds__(256,2)
void k_xwf(const bf16* __restrict__ fH, const bf16* __restrict__ fL,
           const bf16* __restrict__ Wfc, float* __restrict__ XWf, int Mtot)
{
  __shared__ bf16 As[128][32];
  __shared__ bf16 BsH[128][32];
  __shared__ bf16 BsL[128][32];
  const int tid=threadIdx.x;
  const int w=tid>>6, lane=tid&63;
  const int m0=blockIdx.y*128, n0=blockIdx.x*128;

  size_t frowA[2];
  #pragma unroll
  for(int i=0;i<2;++i){
    int r=w*16+i*64+(lane>>2);
    int m=m0+r; if(m>=Mtot) m=Mtot-1;
    int t=m/NINT; int j=1024+(m-t*NINT);
    frowA[i]=((size_t)t*NPT+j)*768;
  }
  const bf16* bPtr[2];
  #pragma unroll
  for(int i=0;i<2;++i){
    int row=n0+(w*2+i)*16+(lane>>2);
    bPtr[i]=Wfc+(size_t)row*1536;
  }
  const int acol=(lane&3)*8;

  f32x4 acc[4][4];
  #pragma unroll
  for(int mi=0;mi<4;++mi)
    #pragma unroll
    for(int ni=0;ni<4;++ni) acc[mi][ni]=(f32x4){0.f,0.f,0.f,0.f};

  const int wr=(w>>1)*64, wc=(w&1)*64;
  const int lr=lane&15, lg=lane>>4;

  auto STEP=[&](const bf16* a0, const bf16* a1, int offH, int offL, bool dual){
    gll16(a0,&As[w*16][0]);
    gll16(a1,&As[w*16+64][0]);
    #pragma unroll
    for(int i=0;i<2;++i) gll16(bPtr[i]+offH+acol,&BsH[(w*2+i)*16][0]);
    if(dual){
      #pragma unroll
      for(int i=0;i<2;++i) gll16(bPtr[i]+offL+acol,&BsL[(w*2+i)*16][0]);
    }
    __syncthreads();
    bf16x8 av[4];
    #pragma unroll
    for(int mi=0;mi<4;++mi) av[mi]=*(bf16x8*)&As[wr+mi*16+lr][lg*8];
    #pragma unroll
    for(int ni=0;ni<4;++ni){
      bf16x8 bvh=*(bf16x8*)&BsH[wc+ni*16+lr][lg*8];
      #pragma unroll
      for(int mi=0;mi<4;++mi)
        acc[mi][ni]=__builtin_amdgcn_mfma_f32_16x16x32_bf16(av[mi],bvh,acc[mi][ni],0,0,0);
      if(dual){
        bf16x8 bvl=*(bf16x8*)&BsL[wc+ni*16+lr][lg*8];
        #pragma unroll
        for(int mi=0;mi<4;++mi)
          acc[mi][ni]=__builtin_amdgcn_mfma_f32_16x16x32_bf16(av[mi],bvl,acc[mi][ni],0,0,0);
      }
    }
    __syncthreads();
  };

  for(int s=0;s<24;++s){ int kk=s<<5;
    STEP(fH+frowA[0]+kk+acol, fH+frowA[1]+kk+acol, kk, 768+kk, true); }
  for(int s=0;s<24;++s){ int kk=s<<5;
    STEP(fL+frowA[0]+kk+acol, fL+frowA[1]+kk+acol, kk, 0, false); }

  #pragma unroll
  for(int mi=0;mi<4;++mi){
    #pragma unroll
    for(int ni=0;ni<4;++ni){
      const int col=n0+wc+ni*16+lr;
      #pragma unroll
      for(int r=0;r<4;++r){
        const int mm=m0+wr+mi*16+lg*4+r;
        if(mm<Mtot) XWf[(size_t)mm*512+col]=acc[mi][ni][r];
      }
    }
  }
}

// ================= Uh-only forget-gate GEMM + fused epilogue (csum + hsum) =================
// grid: (4, E/128). Epilogue also produces hs_hi/hs_lo (fp32 child-sum, split).
__global__ __launch_bounds__(256,2)
void k_uh_f(const bf16* __restrict__ hhi, const bf16* __restrict__ hlo,
            const bf16* __restrict__ Ufc, const float* __restrict__ bias,
            const float* __restrict__ XWf, const float* __restrict__ cbuf,
            float* __restrict__ csum, bf16* __restrict__ hs_hi, bf16* __restrict__ hs_lo,
            int start_ch, int lc, int xwoff)
{
  __shared__ bf16 As[128][32];
  __shared__ bf16 BsH[128][32];
  __shared__ bf16 BsL[128][32];
  const int tid=threadIdx.x;
  const int w=tid>>6, lane=tid&63;
  const int e0=blockIdx.y*128, n0=blockIdx.x*128;

  size_t hrowA[2];
  #pragma unroll
  for(int i=0;i<2;++i){
    int r=w*16+i*64+(lane>>2);
    int e=e0+r;
    int t=e>>lc, ei=e-(t<<lc);
    hrowA[i]=((size_t)t*NPT+start_ch+ei)*HD;
  }
  const bf16* bPtr[2];
  #pragma unroll
  for(int i=0;i<2;++i){
    int row=n0+(w*2+i)*16+(lane>>2);
    bPtr[i]=Ufc+(size_t)row*1024;
  }
  const int acol=(lane&3)*8;

  f32x4 acc[4][4];
  #pragma unroll
  for(int mi=0;mi<4;++mi)
    #pragma unroll
    for(int ni=0;ni<4;++ni) acc[mi][ni]=(f32x4){0.f,0.f,0.f,0.f};

  const int wr=(w>>1)*64, wc=(w&1)*64;
  const int lr=lane&15, lg=lane>>4;

  auto STEP=[&](const bf16* a0, const bf16* a1, int offH, int offL, bool dual){
    gll16(a0,&As[w*16][0]);
    gll16(a1,&As[w*16+64][0]);
    #pragma unroll
    for(int i=0;i<2;++i) gll16(bPtr[i]+offH+acol,&BsH[(w*2+i)*16][0]);
    if(dual){
      #pragma unroll
      for(int i=0;i<2;++i) gll16(bPtr[i]+offL+acol,&BsL[(w*2+i)*16][0]);
    }
    __syncthreads();
    bf16x8 av[4];
    #pragma unroll
    for(int mi=0;mi<4;++mi) av[mi]=*(bf16x8*)&As[wr+mi*16+lr][lg*8];
    #pragma unroll
    for(int ni=0;ni<4;++ni){
      bf16x8 bvh=*(bf16x8*)&BsH[wc+ni*16+lr][lg*8];
      #pragma unroll
      for(int mi=0;mi<4;++mi)
        acc[mi][ni]=__builtin_amdgcn_mfma_f32_16x16x32_bf16(av[mi],bvh,acc[mi][ni],0,0,0);
      if(dual){
        bf16x8 bvl=*(bf16x8*)&BsL[wc+ni*16+lr][lg*8];
        #pragma unroll
        for(int mi=0;mi<4;++mi)
          acc[mi][ni]=__builtin_amdgcn_mfma_f32_16x16x32_bf16(av[mi],bvl,acc[mi][ni],0,0,0);
      }
    }
    __syncthreads();
  };

  for(int s=0;s<16;++s){ int kk=s<<5;
    STEP(hhi+hrowA[0]+kk+acol, hhi+hrowA[1]+kk+acol, kk, 512+kk, true); }
  for(int s=0;s<16;++s){ int kk=s<<5;
    STEP(hlo+hrowA[0]+kk+acol, hlo+hrowA[1]+kk+acol, kk, 0, false); }

  #pragma unroll
  for(int mi=0;mi<4;++mi){
    const int ebase=e0+wr+mi*16+lg*4;
    const int tt=ebase>>lc, eib=ebase-(tt<<lc);
    const int inode=tt*NINT + xwoff + (eib>>2);
    const int par=ebase>>2;
    #pragma unroll
    for(int ni=0;ni<4;++ni){
      const int col=n0+wc+ni*16+lr;
      const float base=bias[col]+XWf[(size_t)inode*512+col];
      const size_t chbase=((size_t)tt*NPT+start_ch+eib)*HD+col;
      float s=0.f, hsv=0.f;
      #pragma unroll
      for(int r=0;r<4;++r){
        const size_t ci=chbase+(size_t)r*HD;
        float fv=sigm(acc[mi][ni][r]+base);
        s+=fv*cbuf[ci];
        hsv+=(float)hhi[ci]+(float)hlo[ci];
      }
      csum[(size_t)par*HD+col]=s;
      bf16 hh=(bf16)hsv;
      hs_hi[(size_t)par*HD+col]=hh;
      hs_lo[(size_t)par*HD+col]=(bf16)(hsv-(float)hh);
    }
  }
}

// ---------------- final head: y = (h_hi+h_lo) @ Wy^T, LayerNorm(4), softmax ----------------
__global__ __launch_bounds__(256)
void k_final2(const bf16* __restrict__ hhi, const bf16* __restrict__ hlo,
              const float* __restrict__ Wy, const float* __restrict__ gamma,
              const float* __restrict__ beta, float* __restrict__ out0, int Nn)
{
  const int gtid=blockIdx.x*256+threadIdx.x;
  const int node=gtid>>6, lane=gtid&63;
  if(node>=Nn) return;
  const size_t base=(size_t)node*HD+lane*8;
  bf16x8 hv=*(const bf16x8*)(hhi+base);
  bf16x8 lv=*(const bf16x8*)(hlo+base);
  float hf[8];
  #pragma unroll
  for(int e=0;e<8;++e) hf[e]=(float)hv[e]+(float)lv[e];
  float y[4];
  #pragma unroll
  for(int jj=0;jj<4;++jj){
    const float* wp=Wy+jj*HD+lane*8;
    float s=0.f;
    #pragma unroll
    for(int e=0;e<8;++e) s+=hf[e]*wp[e];
    #pragma unroll
    for(int off=32;off>=1;off>>=1) s+=__shfl_xor(s,off,64);
    y[jj]=s;
  }
  if(lane==0){
    float mu=0.25f*(y[0]+y[1]+y[2]+y[3]);
    float var=0.f;
    #pragma unroll
    for(int jj=0;jj<4;++jj){ float d=y[jj]-mu; var+=d*d; }
    var*=0.25f;
    float rs=rsqrtf(var+1e-6f);
    float z[4], zmax=-1e30f;
    #pragma unroll
    for(int jj=0;jj<4;++jj){ z[jj]=(y[jj]-mu)*rs*gamma[jj]+beta[jj]; zmax=fmaxf(zmax,z[jj]); }
    float es=0.f;
    #pragma unroll
    for(int jj=0;jj<4;++jj){ z[jj]=__expf(z[jj]-zmax); es+=z[jj]; }
    float inv=1.f/es;
    #pragma unroll
    for(int jj=0;jj<4;++jj) out0[(size_t)node*4+jj]=z[jj]*inv;
  }
}

// ---------------- root head ----------------
__global__ __launch_bounds__(256)
void k_root(const bf16* __restrict__ hhi, const bf16* __restrict__ hlo,
            const float* __restrict__ Wff, float* __restrict__ out1)
{
  const int gtid=blockIdx.x*256+threadIdx.x;
  const int tt=gtid>>6, lane=gtid&63;
  if(tt>=64) return;
  const size_t base=((size_t)tt*NPT+1364)*HD+lane*8;
  bf16x8 hv=*(const bf16x8*)(hhi+base);
  bf16x8 lv=*(const bf16x8*)(hlo+base);
  float hf[8];
  #pragma unroll
  for(int e=0;e<8;++e) hf[e]=(float)hv[e]+(float)lv[e];
  float y[4];
  #pragma unroll
  for(int jj=0;jj<4;++jj){
    const float* wp=Wff+jj*HD+lane*8;
    float s=0.f;
    #pragma unroll
    for(int e=0;e<8;++e) s+=hf[e]*wp[e];
    #pragma unroll
    for(int off=32;off>=1;off>>=1) s+=__shfl_xor(s,off,64);
    y[jj]=s;
  }
  if(lane==0){
    float zmax=fmaxf(fmaxf(y[0],y[1]),fmaxf(y[2],y[3]));
    float es=0.f, z[4];
    #pragma unroll
    for(int jj=0;jj<4;++jj){ z[jj]=__expf(y[jj]-zmax); es+=z[jj]; }
    float inv=1.f/es;
    #pragma unroll
    for(int jj=0;jj<4;++jj) out1[(size_t)tt*4+jj]=z[jj]*inv;
  }
}

extern "C" void kernel_launch(void* const* d_in, const int* in_sizes, int n_in,
                              void* d_out, int out_size, void* d_ws, size_t ws_size,
                              hipStream_t stream)
{
  const float* features=(const float*)d_in[0];
  const float* W_iou=(const float*)d_in[6];
  const float* b_iou=(const float*)d_in[7];
  const float* U_iou=(const float*)d_in[8];
  const float* W_f  =(const float*)d_in[9];
  const float* b_f  =(const float*)d_in[10];
  const float* U_f  =(const float*)d_in[11];
  const float* W_ff =(const float*)d_in[12];
  const float* W_sd =(const float*)d_in[13];
  const float* W_sd2=(const float*)d_in[14];
  const float* W_sf =(const float*)d_in[15];
  const float* ln_g =(const float*)d_in[16];
  const float* ln_b =(const float*)d_in[17];

  const int N=in_sizes[0]/768;   // 87360
  const int T=N/NPT;             // 64
  const int MINT=T*NINT;         // 21824 internal nodes

  float* out0=(float*)d_out;
  float* out1=out0+(size_t)N*4;
  float* cbuf=out1+(size_t)T*4;  // c output region, used as live c-state

  char* p=(char*)d_ws;
  auto alloc=[&](size_t bytes){ char* r=p; p+=((bytes+255)&~(size_t)255); return r; };
  bf16*  f_hi =(bf16*) alloc((size_t)N*768*2);
  bf16*  f_lo =(bf16*) alloc((size_t)N*768*2);
  bf16*  hs_hi=(bf16*) alloc((size_t)16384*HD*2);
  bf16*  hs_lo=(bf16*) alloc((size_t)16384*HD*2);
  float* csum =(float*)alloc((size_t)16384*HD*4);
  bf16*  h_hi =(bf16*) alloc((size_t)N*HD*2);
  bf16*  h_lo =(bf16*) alloc((size_t)N*HD*2);
  bf16*  WcatI2=(bf16*)alloc((size_t)1536*2560*2);
  bf16*  WcatI =(bf16*)alloc((size_t)1536*3840*2);   // level-5 64-tile layout
  bf16*  Wfc  =(bf16*) alloc((size_t)512*1536*2);
  bf16*  Ufc  =(bf16*) alloc((size_t)512*1024*2);
  float* Wcomb=(float*)alloc((size_t)512*512*4);
  float* Wy   =(float*)alloc((size_t)4*512*4);
  float* XWf  =(float*)alloc((size_t)MINT*512*4);

  // conversions / weight prep
  { size_t n8=(size_t)N*768/8;  k_split8<<<(int)((n8+255)/256),256,0,stream>>>(features,f_hi,f_lo,n8); }
  { size_t n=(size_t)1536*2560; k_concat2560<<<(int)((n+255)/256),256,0,stream>>>(W_iou,U_iou,WcatI2,1536); }
  { size_t n=(size_t)1536*3840; k_concatHL3840<<<(int)((n+255)/256),256,0,stream>>>(W_iou,U_iou,WcatI,1536); }
  { size_t n=(size_t)512*1536;  k_catHL<<<(int)((n+255)/256),256,0,stream>>>(W_f,Wfc,512,768); }
  { size_t n=(size_t)512*1024;  k_catHL<<<(int)((n+255)/256),256,0,stream>>>(U_f,Ufc,512,512); }
  { dim3 g(8,8); k_wcomb<<<g,256,0,stream>>>(W_sd2,W_sd,Wcomb); }
  { k_wy<<<8,256,0,stream>>>(W_sf,Wcomb,Wy); }

  // upfront: XWf for all internal nodes (independent of recursion)
  { dim3 g(4,(MINT+127)/128);
    k_xwf<<<g,256,0,stream>>>(f_hi,f_lo,Wfc,XWf,MINT); }

  static const int starts[6]={0,1024,1280,1344,1360,1364};
  static const int csh[6]  ={10,8,6,4,2,0};
  static const int counts[6]={1024,256,64,16,4,1};
  static const int xwoffs[6]={0,0,256,320,336,340};

  // level 0 (leaves)
  { dim3 g(8,(T*1024)/128);
    k_iou128<<<g,256,0,stream>>>(f_hi,f_lo,hs_hi,hs_lo,WcatI2,b_iou,csum,h_hi,h_lo,cbuf,0,10,0); }

  for(int n=1;n<6;++n){
    int P=T*counts[n], E=T*counts[n-1];
    { dim3 g(4,E/128);
      k_uh_f<<<g,256,0,stream>>>(h_hi,h_lo,Ufc,b_f,XWf,cbuf,csum,hs_hi,hs_lo,
                                 starts[n-1],csh[n-1],xwoffs[n]); }
    if(P>=128){
      dim3 g(8,P/128);
      k_iou128<<<g,256,0,stream>>>(f_hi,f_lo,hs_hi,hs_lo,WcatI2,b_iou,csum,h_hi,h_lo,cbuf,starts[n],csh[n],1);
    }else{
      dim3 g(P/64,8);
      k_iou<<<g,256,0,stream>>>(f_hi,f_lo,hs_hi,hs_lo,WcatI,b_iou,csum,h_hi,h_lo,cbuf,starts[n],csh[n],3840,3840,1);
    }
  }

  // heads (stance folded into Wy)
  { int th=N*64; k_final2<<<(th+255)/256,256,0,stream>>>(h_hi,h_lo,Wy,ln_g,ln_b,out0,N); }
  { k_root<<<16,256,0,stream>>>(h_hi,h_lo,W_ff,out1); }
}